// Round 3
// baseline (1103.495 us; speedup 1.0000x reference)
//
#include <hip/hip_runtime.h>
#include <math.h>

#define EMB 1024
#define NHEADS 16
#define HDIM 64
#define BATCH 2
#define SEQ 2048
#define MROWS (BATCH*SEQ)   /* 4096 */
#define LN_EPS 1e-5f

// ---------------------------------------------------------------------------
// GEMM (NT): C[M,N] = A[M,K] @ B[N,K]^T (+ bias). Both A and B row-major with
// contiguous K — ideal coalesced float4 loads on both operands.
// BM=128, BN=64, BK=16, 256 threads, 8x4 microtile per thread.
// ---------------------------------------------------------------------------
template<bool BIAS>
__global__ __launch_bounds__(256)
void gemm_nt(const float* __restrict__ A, const float* __restrict__ Bm,
             const float* __restrict__ bias, float* __restrict__ C,
             int M, int N, int K)
{
    __shared__ float As[16][132];   // [k][m], pad 132 (528B rows: 16B aligned)
    __shared__ float Bs[16][68];    // [k][n], pad 68  (272B rows: 16B aligned)

    const int t  = threadIdx.x;
    const int tx = t & 15;          // n-block  (4 cols)
    const int ty = t >> 4;          // m-block  (8 rows)
    const int m0 = blockIdx.y * 128;
    const int n0 = blockIdx.x * 64;

    const int lrow = t >> 2;        // 0..63
    const int lk4  = t & 3;         // 0..3 -> float4 within 16-wide K slab

    float acc[8][4];
    #pragma unroll
    for (int i = 0; i < 8; ++i)
        #pragma unroll
        for (int j = 0; j < 4; ++j) acc[i][j] = 0.f;

    for (int k0 = 0; k0 < K; k0 += 16) {
        // stage A tile (128x16) transposed -> As[k][m]
        #pragma unroll
        for (int it = 0; it < 2; ++it) {
            const int r = lrow + it * 64;
            const float4 v = *(const float4*)&A[(size_t)(m0 + r) * K + k0 + lk4 * 4];
            As[lk4*4+0][r] = v.x; As[lk4*4+1][r] = v.y;
            As[lk4*4+2][r] = v.z; As[lk4*4+3][r] = v.w;
        }
        // stage B tile (64x16) transposed -> Bs[k][n]
        {
            const float4 v = *(const float4*)&Bm[(size_t)(n0 + lrow) * K + k0 + lk4 * 4];
            Bs[lk4*4+0][lrow] = v.x; Bs[lk4*4+1][lrow] = v.y;
            Bs[lk4*4+2][lrow] = v.z; Bs[lk4*4+3][lrow] = v.w;
        }
        __syncthreads();

        #pragma unroll
        for (int k = 0; k < 16; ++k) {
            const float4 a0 = *(const float4*)&As[k][ty*8];
            const float4 a1 = *(const float4*)&As[k][ty*8+4];
            const float4 b0 = *(const float4*)&Bs[k][tx*4];
            const float am[8] = {a0.x,a0.y,a0.z,a0.w,a1.x,a1.y,a1.z,a1.w};
            const float bn[4] = {b0.x,b0.y,b0.z,b0.w};
            #pragma unroll
            for (int i = 0; i < 8; ++i)
                #pragma unroll
                for (int j = 0; j < 4; ++j)
                    acc[i][j] = fmaf(am[i], bn[j], acc[i][j]);
        }
        __syncthreads();
    }

    float4 bb = make_float4(0.f, 0.f, 0.f, 0.f);
    if (BIAS) bb = *(const float4*)&bias[n0 + tx*4];
    #pragma unroll
    for (int i = 0; i < 8; ++i) {
        float4 o;
        o.x = acc[i][0] + bb.x; o.y = acc[i][1] + bb.y;
        o.z = acc[i][2] + bb.z; o.w = acc[i][3] + bb.w;
        *(float4*)&C[(size_t)(m0 + ty*8 + i) * N + n0 + tx*4] = o;
    }
}

// ---------------------------------------------------------------------------
// Per-head LayerNorm over 64-wide contiguous rows, fused with emb^(-1/4).
// One wave per row; 4 rows per 256-thread block.
// ---------------------------------------------------------------------------
__global__ __launch_bounds__(256)
void ln_head(float* __restrict__ X, const float* __restrict__ g,
             const float* __restrict__ b, float scale, int nrows)
{
    const int w    = blockIdx.x * 4 + (threadIdx.x >> 6);
    const int lane = threadIdx.x & 63;
    if (w >= nrows) return;
    const size_t idx = (size_t)w * 64 + lane;
    const float v = X[idx];

    float s = v;
    #pragma unroll
    for (int m = 32; m >= 1; m >>= 1) s += __shfl_xor(s, m);
    const float mu = s * (1.f / 64.f);

    const float d  = v - mu;
    float s2 = d * d;
    #pragma unroll
    for (int m = 32; m >= 1; m >>= 1) s2 += __shfl_xor(s2, m);
    const float var = s2 * (1.f / 64.f);

    const float xhat = d * rsqrtf(var + LN_EPS);
    X[idx] = (xhat * g[lane] + b[lane]) * scale;
}

// ---------------------------------------------------------------------------
// Causal flash attention, fp32 vector. One block per (b, h, 64-row q tile).
// - Register online softmax: 16-lane row groups, __shfl_xor(1,2,4,8) reduce.
//   No LDS softmax traffic, no rowm/rowl arrays.
// - LDS reuse: U holds K^T during QK^T, then P during PV (K dead after QK^T).
//   P rows are wave-local (row group == one wave) -> lgkmcnt(0) suffices, no
//   extra barrier. LDS = 3*64*68*4 = 51 KB -> 3 blocks/CU.
// - Heavy q-tiles dispatched first (qt reversed) to shrink the causal tail.
// ---------------------------------------------------------------------------
__global__ __launch_bounds__(256)
void attn_fwd(const float* __restrict__ Q, const float* __restrict__ K,
              const float* __restrict__ V, float* __restrict__ O)
{
    __shared__ float Qt[64][68];   // [d][q]
    __shared__ float U [64][68];   // K^T [d][k] in phase A; P [q][k] in phase C
    __shared__ float Vs[64][68];   // [k][d]

    const int t  = threadIdx.x;
    const int qt = (int)gridDim.x - 1 - (int)blockIdx.x;   // heavy tiles first
    const int bh = blockIdx.y;               // b*NHEADS + h
    const int bb = bh >> 4, hh = bh & 15;
    const size_t base = (size_t)bb * SEQ * EMB + (size_t)hh * HDIM;
    const int q0 = qt * 64;

    const int tx = t & 15;                   // k cols (4)
    const int ty = t >> 4;                   // q rows (4)
    const int d4 = t & 15, r0 = t >> 4;      // staging roles

    // stage Q tile transposed (persists for whole block)
    #pragma unroll
    for (int it = 0; it < 4; ++it) {
        const int r = r0 + it * 16;
        const float4 v = *(const float4*)&Q[base + (size_t)(q0 + r) * EMB + d4 * 4];
        Qt[d4*4+0][r] = v.x; Qt[d4*4+1][r] = v.y;
        Qt[d4*4+2][r] = v.z; Qt[d4*4+3][r] = v.w;
    }

    float oacc[4][4];
    float m_run[4], l_run[4];
    #pragma unroll
    for (int i = 0; i < 4; ++i) {
        m_run[i] = -1e30f; l_run[i] = 0.f;
        #pragma unroll
        for (int j = 0; j < 4; ++j) oacc[i][j] = 0.f;
    }

    for (int kt = 0; kt <= qt; ++kt) {
        const int k0 = kt * 64;

        __syncthreads();   // prev iter's P/Vs reads done (also covers Qt stage)

        // stage K (transposed into U) + V tiles
        #pragma unroll
        for (int it = 0; it < 4; ++it) {
            const int r = r0 + it * 16;
            const float4 kv = *(const float4*)&K[base + (size_t)(k0 + r) * EMB + d4 * 4];
            U[d4*4+0][r] = kv.x; U[d4*4+1][r] = kv.y;
            U[d4*4+2][r] = kv.z; U[d4*4+3][r] = kv.w;
            const float4 vv = *(const float4*)&V[base + (size_t)(k0 + r) * EMB + d4 * 4];
            *(float4*)&Vs[r][d4*4] = vv;
        }
        __syncthreads();

        // phase A: S = Q @ K^T
        float s[4][4];
        #pragma unroll
        for (int i = 0; i < 4; ++i)
            #pragma unroll
            for (int j = 0; j < 4; ++j) s[i][j] = 0.f;

        #pragma unroll 8
        for (int d = 0; d < 64; ++d) {
            const float4 a = *(const float4*)&Qt[d][ty*4];
            const float4 b = *(const float4*)&U[d][tx*4];
            const float av[4] = {a.x, a.y, a.z, a.w};
            const float bv[4] = {b.x, b.y, b.z, b.w};
            #pragma unroll
            for (int i = 0; i < 4; ++i)
                #pragma unroll
                for (int j = 0; j < 4; ++j)
                    s[i][j] = fmaf(av[i], bv[j], s[i][j]);
        }
        if (kt == qt) {   // causal mask inside diagonal tile (diag kept)
            #pragma unroll
            for (int i = 0; i < 4; ++i)
                #pragma unroll
                for (int j = 0; j < 4; ++j)
                    if (tx*4 + j > ty*4 + i) s[i][j] = -1e30f;
        }

        // phase B: register online softmax (per-row, replicated over 16 lanes)
        float sc[4];
        #pragma unroll
        for (int i = 0; i < 4; ++i) {
            float mx = fmaxf(fmaxf(s[i][0], s[i][1]), fmaxf(s[i][2], s[i][3]));
            mx = fmaxf(mx, __shfl_xor(mx, 1));
            mx = fmaxf(mx, __shfl_xor(mx, 2));
            mx = fmaxf(mx, __shfl_xor(mx, 4));
            mx = fmaxf(mx, __shfl_xor(mx, 8));
            const float mnew = fmaxf(m_run[i], mx);
            sc[i] = __expf(m_run[i] - mnew);
            m_run[i] = mnew;
            float ls = 0.f;
            #pragma unroll
            for (int j = 0; j < 4; ++j) {
                const float p = __expf(s[i][j] - mnew);
                s[i][j] = p;
                ls += p;
            }
            ls += __shfl_xor(ls, 1);
            ls += __shfl_xor(ls, 2);
            ls += __shfl_xor(ls, 4);
            ls += __shfl_xor(ls, 8);
            l_run[i] = l_run[i] * sc[i] + ls;
            #pragma unroll
            for (int j = 0; j < 4; ++j) oacc[i][j] *= sc[i];
        }

        __syncthreads();   // all waves done reading U as K^T

        // write P into U (wave-local rows: row group == one wave)
        #pragma unroll
        for (int i = 0; i < 4; ++i) {
            float4 o;
            o.x = s[i][0]; o.y = s[i][1]; o.z = s[i][2]; o.w = s[i][3];
            *(float4*)&U[ty*4 + i][tx*4] = o;
        }
        asm volatile("s_waitcnt lgkmcnt(0)" ::: "memory");  // wave-local P ready

        // phase C: oacc += P @ V
        #pragma unroll 4
        for (int k4 = 0; k4 < 16; ++k4) {
            float4 p[4], v[4];
            #pragma unroll
            for (int i = 0; i < 4; ++i) p[i] = *(const float4*)&U[ty*4 + i][k4*4];
            #pragma unroll
            for (int kk = 0; kk < 4; ++kk) v[kk] = *(const float4*)&Vs[k4*4 + kk][tx*4];
            #pragma unroll
            for (int i = 0; i < 4; ++i) {
                const float pv[4] = {p[i].x, p[i].y, p[i].z, p[i].w};
                #pragma unroll
                for (int kk = 0; kk < 4; ++kk) {
                    const float vv[4] = {v[kk].x, v[kk].y, v[kk].z, v[kk].w};
                    oacc[i][0] = fmaf(pv[kk], vv[0], oacc[i][0]);
                    oacc[i][1] = fmaf(pv[kk], vv[1], oacc[i][1]);
                    oacc[i][2] = fmaf(pv[kk], vv[2], oacc[i][2]);
                    oacc[i][3] = fmaf(pv[kk], vv[3], oacc[i][3]);
                }
            }
        }
    }

    // epilogue: normalize by row sum, write O in [b, t, h, d] layout
    #pragma unroll
    for (int i = 0; i < 4; ++i) {
        const float inv = 1.f / l_run[i];
        float4 o;
        o.x = oacc[i][0] * inv; o.y = oacc[i][1] * inv;
        o.z = oacc[i][2] * inv; o.w = oacc[i][3] * inv;
        *(float4*)&O[base + (size_t)(q0 + ty*4 + i) * EMB + tx*4] = o;
    }
}

// ---------------------------------------------------------------------------
extern "C" void kernel_launch(void* const* d_in, const int* in_sizes, int n_in,
                              void* d_out, int out_size, void* d_ws, size_t ws_size,
                              hipStream_t stream)
{
    const float* x  = (const float*)d_in[0];
    const float* Wk = (const float*)d_in[1];
    const float* Wq = (const float*)d_in[2];
    const float* Wv = (const float*)d_in[3];
    const float* Wu = (const float*)d_in[4];
    const float* bu = (const float*)d_in[5];
    const float* kg = (const float*)d_in[6];
    const float* kb = (const float*)d_in[7];
    const float* qg = (const float*)d_in[8];
    const float* qb = (const float*)d_in[9];
    float* out = (float*)d_out;

    const size_t NELEM = (size_t)MROWS * EMB;       // 4,194,304 floats = 16 MB
    float* Kb = (float*)d_ws;                        // needs 64 MB of ws total
    float* Qb = Kb + NELEM;
    float* Vb = Qb + NELEM;
    float* Ob = Vb + NELEM;

    const dim3 gg(EMB / 64, MROWS / 128);            // (16, 32)

    gemm_nt<false><<<gg, 256, 0, stream>>>(x, Wk, nullptr, Kb, MROWS, EMB, EMB);
    gemm_nt<false><<<gg, 256, 0, stream>>>(x, Wq, nullptr, Qb, MROWS, EMB, EMB);
    gemm_nt<false><<<gg, 256, 0, stream>>>(x, Wv, nullptr, Vb, MROWS, EMB, EMB);

    const float inv4 = 0.17677669529663687f;         // 1024^(-1/4) = 2^(-2.5)
    const int head_rows = MROWS * NHEADS;            // 65536 per tensor
    ln_head<<<head_rows / 4, 256, 0, stream>>>(Kb, kg, kb, inv4, head_rows);
    ln_head<<<head_rows / 4, 256, 0, stream>>>(Qb, qg, qb, inv4, head_rows);

    attn_fwd<<<dim3(SEQ / 64, BATCH * NHEADS), 256, 0, stream>>>(Qb, Kb, Vb, Ob);

    gemm_nt<true><<<gg, 256, 0, stream>>>(Ob, Wu, bu, out, MROWS, EMB, EMB);
}

// Round 4
// 741.569 us; speedup vs baseline: 1.4881x; 1.4881x over previous
//
#include <hip/hip_runtime.h>
#include <math.h>

#define EMB 1024
#define NHEADS 16
#define HDIM 64
#define BATCH 2
#define SEQ 2048
#define MROWS (BATCH*SEQ)   /* 4096 */
#define LN_EPS 1e-5f

typedef __attribute__((ext_vector_type(8))) short bf16x8;
typedef __attribute__((ext_vector_type(4))) float f32x4;
typedef __attribute__((ext_vector_type(4))) int int4v;

__device__ __forceinline__ short f2bf(float f) {     // RNE float->bf16
    union { float f; unsigned u; } v; v.f = f;
    unsigned r = v.u + 0x7FFFu + ((v.u >> 16) & 1u);
    return (short)(r >> 16);
}
__device__ __forceinline__ float bf2f(short s) {
    union { unsigned u; float f; } v; v.u = ((unsigned)(unsigned short)s) << 16;
    return v.f;
}

// ---------------------------------------------------------------------------
// GEMM (NT): C[M,N] = A[M,K] @ B[N,K]^T (+ bias). fp32 VALU (unchanged).
// ---------------------------------------------------------------------------
template<bool BIAS>
__global__ __launch_bounds__(256)
void gemm_nt(const float* __restrict__ A, const float* __restrict__ Bm,
             const float* __restrict__ bias, float* __restrict__ C,
             int M, int N, int K)
{
    __shared__ float As[16][132];
    __shared__ float Bs[16][68];

    const int t  = threadIdx.x;
    const int tx = t & 15;
    const int ty = t >> 4;
    const int m0 = blockIdx.y * 128;
    const int n0 = blockIdx.x * 64;

    const int lrow = t >> 2;
    const int lk4  = t & 3;

    float acc[8][4];
    #pragma unroll
    for (int i = 0; i < 8; ++i)
        #pragma unroll
        for (int j = 0; j < 4; ++j) acc[i][j] = 0.f;

    for (int k0 = 0; k0 < K; k0 += 16) {
        #pragma unroll
        for (int it = 0; it < 2; ++it) {
            const int r = lrow + it * 64;
            const float4 v = *(const float4*)&A[(size_t)(m0 + r) * K + k0 + lk4 * 4];
            As[lk4*4+0][r] = v.x; As[lk4*4+1][r] = v.y;
            As[lk4*4+2][r] = v.z; As[lk4*4+3][r] = v.w;
        }
        {
            const float4 v = *(const float4*)&Bm[(size_t)(n0 + lrow) * K + k0 + lk4 * 4];
            Bs[lk4*4+0][lrow] = v.x; Bs[lk4*4+1][lrow] = v.y;
            Bs[lk4*4+2][lrow] = v.z; Bs[lk4*4+3][lrow] = v.w;
        }
        __syncthreads();

        #pragma unroll
        for (int k = 0; k < 16; ++k) {
            const float4 a0 = *(const float4*)&As[k][ty*8];
            const float4 a1 = *(const float4*)&As[k][ty*8+4];
            const float4 b0 = *(const float4*)&Bs[k][tx*4];
            const float am[8] = {a0.x,a0.y,a0.z,a0.w,a1.x,a1.y,a1.z,a1.w};
            const float bn[4] = {b0.x,b0.y,b0.z,b0.w};
            #pragma unroll
            for (int i = 0; i < 8; ++i)
                #pragma unroll
                for (int j = 0; j < 4; ++j)
                    acc[i][j] = fmaf(am[i], bn[j], acc[i][j]);
        }
        __syncthreads();
    }

    float4 bb = make_float4(0.f, 0.f, 0.f, 0.f);
    if (BIAS) bb = *(const float4*)&bias[n0 + tx*4];
    #pragma unroll
    for (int i = 0; i < 8; ++i) {
        float4 o;
        o.x = acc[i][0] + bb.x; o.y = acc[i][1] + bb.y;
        o.z = acc[i][2] + bb.z; o.w = acc[i][3] + bb.w;
        *(float4*)&C[(size_t)(m0 + ty*8 + i) * N + n0 + tx*4] = o;
    }
}

// ---------------------------------------------------------------------------
// Per-head LayerNorm fused with emb^(-1/4) scale; emits split-bf16 (hi,lo)
// head panels in [b][h][t][d] layout. One wave per 64-wide row.
// ---------------------------------------------------------------------------
__global__ __launch_bounds__(256)
void ln_head_split(const float* __restrict__ X, const float* __restrict__ g,
                   const float* __restrict__ b, float scale,
                   short* __restrict__ Hh, short* __restrict__ Hl)
{
    const int w    = blockIdx.x * 4 + (threadIdx.x >> 6);   // row over (b,t,h)
    const int lane = threadIdx.x & 63;
    const size_t idx = (size_t)w * 64 + lane;
    const float v = X[idx];

    float s = v;
    #pragma unroll
    for (int m = 32; m >= 1; m >>= 1) s += __shfl_xor(s, m);
    const float mu = s * (1.f / 64.f);

    const float d  = v - mu;
    float s2 = d * d;
    #pragma unroll
    for (int m = 32; m >= 1; m >>= 1) s2 += __shfl_xor(s2, m);
    const float var = s2 * (1.f / 64.f);

    const float y = (d * rsqrtf(var + LN_EPS) * g[lane] + b[lane]) * scale;

    const int bb = w >> 15;              // w = (b*SEQ + t)*16 + h
    const int tt = (w >> 4) & (SEQ - 1);
    const int hh = w & 15;
    const size_t o = ((size_t)(bb * NHEADS + hh) * SEQ + tt) * HDIM + lane;
    const short hi = f2bf(y);
    Hh[o] = hi;
    Hl[o] = f2bf(y - bf2f(hi));
}

// ---------------------------------------------------------------------------
// V fp32 [b][t][h][d]  ->  split-bf16 V^T panels [b][h][d][t].
// Block per (t-chunk of 64, h, b); LDS transpose.
// ---------------------------------------------------------------------------
__global__ __launch_bounds__(256)
void conv_v(const float* __restrict__ V, short* __restrict__ Vh,
            short* __restrict__ Vl)
{
    __shared__ float S[64][65];          // [t][d], pad 65 (2-way banks on col reads)
    const int t  = threadIdx.x;
    const int t0 = blockIdx.x * 64;
    const int hh = blockIdx.y;
    const int bb = blockIdx.z;

    const int d4 = t & 15, tr = t >> 4;
    #pragma unroll
    for (int it = 0; it < 4; ++it) {
        const int tl = tr + it * 16;
        const float4 v = *(const float4*)
            &V[(((size_t)(bb * SEQ + t0 + tl)) * NHEADS + hh) * HDIM + d4 * 4];
        S[tl][d4*4+0] = v.x; S[tl][d4*4+1] = v.y;
        S[tl][d4*4+2] = v.z; S[tl][d4*4+3] = v.w;
    }
    __syncthreads();

    #pragma unroll
    for (int p = 0; p < 2; ++p) {
        const int c = t + p * 256;       // 512 chunks: d row, 8-t chunk
        const int d = c >> 3, toff = (c & 7) * 8;
        short hi[8], lo[8];
        #pragma unroll
        for (int j = 0; j < 8; ++j) {
            const float f = S[toff + j][d];
            hi[j] = f2bf(f);
            lo[j] = f2bf(f - bf2f(hi[j]));
        }
        const size_t o = ((size_t)(bb * NHEADS + hh) * HDIM + d) * SEQ + t0 + toff;
        *(int4v*)&Vh[o] = *(int4v*)hi;
        *(int4v*)&Vl[o] = *(int4v*)lo;
    }
}

// ---------------------------------------------------------------------------
// Causal flash attention, split-bf16 MFMA (16x16x32). Block = (b,h,64-q tile),
// 4 waves; wave w owns q-stripe [16w,16w+16). Q-frags in registers (loaded
// once). K/V staged bf16 (no conversion in loop). Softmax in C-frag registers
// (row=(lane>>4)*4+reg, col=lane&15). P re-shaped via wave-private LDS.
// 3 MFMAs per product (hi*hi + hi*lo + lo*hi), fp32 accumulate.
// LDS stride 72 shorts: rows 16B-aligned, frag reads <=2-way banks. 54 KB.
// ---------------------------------------------------------------------------
__global__ __launch_bounds__(256)
void attn_mfma(const short* __restrict__ Qh, const short* __restrict__ Ql,
               const short* __restrict__ Kh, const short* __restrict__ Kl,
               const short* __restrict__ Vh, const short* __restrict__ Vl,
               float* __restrict__ O)
{
    __shared__ short KhS[64][72], KlS[64][72];
    __shared__ short VhS[64][72], VlS[64][72];
    __shared__ short PhS[64][72], PlS[64][72];

    const int t    = threadIdx.x;
    const int lane = t & 63, wv = t >> 6;
    const int l15  = lane & 15, l4 = lane >> 4;
    const int qt   = (int)gridDim.x - 1 - (int)blockIdx.x;   // heavy first
    const int bh   = blockIdx.y;
    const int bb   = bh >> 4, hh = bh & 15;
    const int q0   = qt * 64;
    const int wq0  = wv * 16;

    const size_t kpan = (size_t)bh * SEQ * HDIM;   // [t][d] panels (Q,K)
    const size_t vpan = (size_t)bh * HDIM * SEQ;   // [d][t] panels (V^T)

    // Q fragments: A-frag row = lane&15 (q in stripe), k = (lane>>4)*8 + 32*ds
    bf16x8 qfh[2], qfl[2];
    {
        const size_t qrow = kpan + (size_t)(q0 + wq0 + l15) * HDIM;
        #pragma unroll
        for (int ds = 0; ds < 2; ++ds) {
            qfh[ds] = *(const bf16x8*)&Qh[qrow + l4 * 8 + 32 * ds];
            qfl[ds] = *(const bf16x8*)&Ql[qrow + l4 * 8 + 32 * ds];
        }
    }

    f32x4 oacc[4];
    float m_run[4], l_run[4];
    #pragma unroll
    for (int r = 0; r < 4; ++r) { m_run[r] = -1e30f; l_run[r] = 0.f; }
    #pragma unroll
    for (int nf = 0; nf < 4; ++nf) oacc[nf] = (f32x4){0.f, 0.f, 0.f, 0.f};

    for (int kt = 0; kt <= qt; ++kt) {
        const int k0 = kt * 64;

        __syncthreads();   // prior tile's K/V frag reads complete

        // stage K (hi,lo) and V^T (hi,lo) tiles: 512 16B-chunks per plane
        #pragma unroll
        for (int p = 0; p < 2; ++p) {
            const int c = t + p * 256;
            const int r = c >> 3, off = (c & 7) * 8;
            *(int4v*)&KhS[r][off] = *(const int4v*)&Kh[kpan + (size_t)(k0 + r) * HDIM + off];
            *(int4v*)&KlS[r][off] = *(const int4v*)&Kl[kpan + (size_t)(k0 + r) * HDIM + off];
            *(int4v*)&VhS[r][off] = *(const int4v*)&Vh[vpan + (size_t)r * SEQ + k0 + off];
            *(int4v*)&VlS[r][off] = *(const int4v*)&Vl[vpan + (size_t)r * SEQ + k0 + off];
        }
        __syncthreads();

        // ---- QK^T: S-stripe 16q x 64k, split-bf16 (3 MFMAs/term) ----
        f32x4 s[4];
        #pragma unroll
        for (int nf = 0; nf < 4; ++nf) s[nf] = (f32x4){0.f, 0.f, 0.f, 0.f};

        #pragma unroll
        for (int ds = 0; ds < 2; ++ds) {
            #pragma unroll
            for (int nf = 0; nf < 4; ++nf) {
                const bf16x8 kh = *(const bf16x8*)&KhS[nf * 16 + l15][l4 * 8 + 32 * ds];
                const bf16x8 kl = *(const bf16x8*)&KlS[nf * 16 + l15][l4 * 8 + 32 * ds];
                s[nf] = __builtin_amdgcn_mfma_f32_16x16x32_bf16(qfh[ds], kh, s[nf], 0, 0, 0);
                s[nf] = __builtin_amdgcn_mfma_f32_16x16x32_bf16(qfh[ds], kl, s[nf], 0, 0, 0);
                s[nf] = __builtin_amdgcn_mfma_f32_16x16x32_bf16(qfl[ds], kh, s[nf], 0, 0, 0);
            }
        }

        if (kt == qt) {     // causal mask in diag tile (diag kept)
            #pragma unroll
            for (int nf = 0; nf < 4; ++nf)
                #pragma unroll
                for (int r = 0; r < 4; ++r) {
                    const int kl_ = nf * 16 + l15;
                    const int ql_ = wq0 + l4 * 4 + r;
                    if (kl_ > ql_) s[nf][r] = -1e30f;
                }
        }

        // ---- online softmax in fragment registers ----
        #pragma unroll
        for (int r = 0; r < 4; ++r) {
            float mx = fmaxf(fmaxf(s[0][r], s[1][r]), fmaxf(s[2][r], s[3][r]));
            mx = fmaxf(mx, __shfl_xor(mx, 1));
            mx = fmaxf(mx, __shfl_xor(mx, 2));
            mx = fmaxf(mx, __shfl_xor(mx, 4));
            mx = fmaxf(mx, __shfl_xor(mx, 8));
            const float mnew = fmaxf(m_run[r], mx);
            const float scf  = __expf(m_run[r] - mnew);
            m_run[r] = mnew;
            float ls = 0.f;
            #pragma unroll
            for (int nf = 0; nf < 4; ++nf) {
                const float p = __expf(s[nf][r] - mnew);
                s[nf][r] = p;
                ls += p;
            }
            ls += __shfl_xor(ls, 1);
            ls += __shfl_xor(ls, 2);
            ls += __shfl_xor(ls, 4);
            ls += __shfl_xor(ls, 8);
            l_run[r] = l_run[r] * scf + ls;
            #pragma unroll
            for (int nf = 0; nf < 4; ++nf) oacc[nf][r] *= scf;
        }

        // ---- P -> wave-private LDS (reshape C-frag -> A-frag) ----
        #pragma unroll
        for (int nf = 0; nf < 4; ++nf)
            #pragma unroll
            for (int r = 0; r < 4; ++r) {
                const float p = s[nf][r];
                const short ph = f2bf(p);
                PhS[wq0 + l4 * 4 + r][nf * 16 + l15] = ph;
                PlS[wq0 + l4 * 4 + r][nf * 16 + l15] = f2bf(p - bf2f(ph));
            }
        asm volatile("s_waitcnt lgkmcnt(0)" ::: "memory");  // wave-local P ready

        // ---- PV: oacc += P @ V^T-panels, split-bf16 ----
        #pragma unroll
        for (int ks = 0; ks < 2; ++ks) {
            const bf16x8 pah = *(const bf16x8*)&PhS[wq0 + l15][l4 * 8 + 32 * ks];
            const bf16x8 pal = *(const bf16x8*)&PlS[wq0 + l15][l4 * 8 + 32 * ks];
            #pragma unroll
            for (int nf = 0; nf < 4; ++nf) {
                const bf16x8 vh = *(const bf16x8*)&VhS[nf * 16 + l15][l4 * 8 + 32 * ks];
                const bf16x8 vl = *(const bf16x8*)&VlS[nf * 16 + l15][l4 * 8 + 32 * ks];
                oacc[nf] = __builtin_amdgcn_mfma_f32_16x16x32_bf16(pah, vh, oacc[nf], 0, 0, 0);
                oacc[nf] = __builtin_amdgcn_mfma_f32_16x16x32_bf16(pah, vl, oacc[nf], 0, 0, 0);
                oacc[nf] = __builtin_amdgcn_mfma_f32_16x16x32_bf16(pal, vh, oacc[nf], 0, 0, 0);
            }
        }
    }

    // epilogue: normalize, write O fp32 [b][t][h*64+d]
    #pragma unroll
    for (int r = 0; r < 4; ++r) {
        const float inv = 1.f / l_run[r];
        const int q = q0 + wq0 + l4 * 4 + r;
        #pragma unroll
        for (int nf = 0; nf < 4; ++nf)
            O[((size_t)(bb * SEQ + q)) * EMB + hh * HDIM + nf * 16 + l15] =
                oacc[nf][r] * inv;
    }
}

// ---------------------------------------------------------------------------
extern "C" void kernel_launch(void* const* d_in, const int* in_sizes, int n_in,
                              void* d_out, int out_size, void* d_ws, size_t ws_size,
                              hipStream_t stream)
{
    const float* x  = (const float*)d_in[0];
    const float* Wk = (const float*)d_in[1];
    const float* Wq = (const float*)d_in[2];
    const float* Wv = (const float*)d_in[3];
    const float* Wu = (const float*)d_in[4];
    const float* bu = (const float*)d_in[5];
    const float* kg = (const float*)d_in[6];
    const float* kb = (const float*)d_in[7];
    const float* qg = (const float*)d_in[8];
    const float* qb = (const float*)d_in[9];
    float* out = (float*)d_out;

    // workspace map (64 MB total, region A reused serially):
    //  A: [0,16M)    fp32 Kb -> Qb -> Vb -> Ob
    //  B: [16M,32M)  Kh | Kl bf16 panels
    //  C: [32M,48M)  Qh | Ql
    //  D: [48M,64M)  Vth | Vtl
    char* w = (char*)d_ws;
    float* fA  = (float*)(w);
    short* KhP = (short*)(w + (16u << 20));
    short* KlP = (short*)(w + (24u << 20));
    short* QhP = (short*)(w + (32u << 20));
    short* QlP = (short*)(w + (40u << 20));
    short* VhP = (short*)(w + (48u << 20));
    short* VlP = (short*)(w + (56u << 20));

    const dim3 gg(EMB / 64, MROWS / 128);            // (16, 32)
    const float inv4 = 0.17677669529663687f;         // 1024^(-1/4)
    const int head_rows = MROWS * NHEADS;            // 65536

    gemm_nt<false><<<gg, 256, 0, stream>>>(x, Wk, nullptr, fA, MROWS, EMB, EMB);
    ln_head_split<<<head_rows / 4, 256, 0, stream>>>(fA, kg, kb, inv4, KhP, KlP);

    gemm_nt<false><<<gg, 256, 0, stream>>>(x, Wq, nullptr, fA, MROWS, EMB, EMB);
    ln_head_split<<<head_rows / 4, 256, 0, stream>>>(fA, qg, qb, inv4, QhP, QlP);

    gemm_nt<false><<<gg, 256, 0, stream>>>(x, Wv, nullptr, fA, MROWS, EMB, EMB);
    conv_v<<<dim3(SEQ / 64, NHEADS, BATCH), 256, 0, stream>>>(fA, VhP, VlP);

    attn_mfma<<<dim3(SEQ / 64, BATCH * NHEADS), 256, 0, stream>>>(
        QhP, QlP, KhP, KlP, VhP, VlP, fA);

    gemm_nt<true><<<gg, 256, 0, stream>>>(fA, Wu, bu, out, MROWS, EMB, EMB);
}

// Round 6
// 421.668 us; speedup vs baseline: 2.6170x; 1.7587x over previous
//
#include <hip/hip_runtime.h>
#include <math.h>

#define EMB 1024
#define NHEADS 16
#define HDIM 64
#define BATCH 2
#define SEQ 2048
#define MROWS (BATCH*SEQ)   /* 4096 */
#define LN_EPS 1e-5f
#define GK 1024
#define GN 1024

typedef __attribute__((ext_vector_type(8))) short bf16x8;
typedef __attribute__((ext_vector_type(4))) short s16x4;
typedef __attribute__((ext_vector_type(4))) float f32x4;
typedef __attribute__((ext_vector_type(4))) int int4v;

__device__ __forceinline__ short f2bf(float f) {     // RNE float->bf16
    union { float f; unsigned u; } v; v.f = f;
    unsigned r = v.u + 0x7FFFu + ((v.u >> 16) & 1u);
    return (short)(r >> 16);
}
__device__ __forceinline__ float bf2f(short s) {
    union { unsigned u; float f; } v; v.u = ((unsigned)(unsigned short)s) << 16;
    return v.f;
}
// truncating split: f = hi + lo + err, |err| <~ 2^-17 |f|
__device__ __forceinline__ void fsplit(float f, short& hi, short& lo) {
    const unsigned u = __float_as_uint(f);
    hi = (short)(u >> 16);
    const float r = f - __uint_as_float(u & 0xFFFF0000u);   // exact
    lo = (short)(__float_as_uint(r) >> 16);
}

__device__ __forceinline__ void gload16(const short* g, short* l) {
    __builtin_amdgcn_global_load_lds(
        (const __attribute__((address_space(1))) unsigned*)g,
        (__attribute__((address_space(3))) unsigned*)l, 16, 0, 0);
}

// ---------------------------------------------------------------------------
// fp32 -> split-bf16 planes (hi, lo). n divisible by 1024.
// ---------------------------------------------------------------------------
__global__ __launch_bounds__(256)
void cvt_split(const float* __restrict__ X, short* __restrict__ H,
               short* __restrict__ L)
{
    const size_t i = (size_t)blockIdx.x * 256 + threadIdx.x;
    const float4 v = *(const float4*)&X[i * 4];
    s16x4 h, l;
    short th, tl;
    fsplit(v.x, th, tl); h[0] = th; l[0] = tl;
    fsplit(v.y, th, tl); h[1] = th; l[1] = tl;
    fsplit(v.z, th, tl); h[2] = th; l[2] = tl;
    fsplit(v.w, th, tl); h[3] = th; l[3] = tl;
    *(s16x4*)&H[i * 4] = h;
    *(s16x4*)&L[i * 4] = l;
}

// ---------------------------------------------------------------------------
// Split-bf16 MFMA GEMM (NT): C[M,N] = A@B^T, A[M,K] B[N,K] as hi/lo planes.
// 128x128 tile, BK=32, 4 waves (2x2, 64x64 each), 16x16x32_bf16,
// 3 MFMAs per fragment pair (hh + hl + lh). global_load_lds staging.
// Epilogue modes: 0 = per-head LN (+scale) -> split panels [b][h][t][d]
//                 1 = split planes row-major [m][n]
//                 2 = fp32 + bias row-major (final output)
// ---------------------------------------------------------------------------
template<int MODE>
__global__ __launch_bounds__(256)
void gemm_mfma(const short* __restrict__ Ah, const short* __restrict__ Al,
               const short* __restrict__ Bh, const short* __restrict__ Bl,
               const float* __restrict__ gamma, const float* __restrict__ beta,
               float scale, const float* __restrict__ bias,
               short* __restrict__ OutH, short* __restrict__ OutL,
               float* __restrict__ OutF)
{
    __shared__ short AhS[128][32], AlS[128][32], BhS[128][32], BlS[128][32];

    const int t   = threadIdx.x;
    const int ln  = t & 63, wv = t >> 6;
    const int l15 = ln & 15, l4 = ln >> 4;
    const int m0  = blockIdx.y * 128;
    const int n0  = blockIdx.x * 128;
    const int wr  = (wv >> 1) * 64, wc = (wv & 1) * 64;

    // each wave stages one plane (128x32 shorts = 8 segs of 1KB)
    const short* gplane = (wv == 0) ? Ah : (wv == 1) ? Al : (wv == 2) ? Bh : Bl;
    const int    grow0  = (wv < 2) ? m0 : n0;
    short* lplane = (wv == 0) ? &AhS[0][0] : (wv == 1) ? &AlS[0][0]
                  : (wv == 2) ? &BhS[0][0] : &BlS[0][0];

    f32x4 acc[4][4];
    #pragma unroll
    for (int i = 0; i < 4; ++i)
        #pragma unroll
        for (int j = 0; j < 4; ++j) acc[i][j] = (f32x4){0.f, 0.f, 0.f, 0.f};

    for (int k0 = 0; k0 < GK; k0 += 32) {
        __syncthreads();                 // prev iter's frag reads complete
        #pragma unroll
        for (int s = 0; s < 8; ++s) {
            const int chunk = s * 64 + ln;
            const int r = chunk >> 2, c = chunk & 3;
            gload16(gplane + (size_t)(grow0 + r) * GK + k0 + c * 8,
                    lplane + s * 512);
        }
        __syncthreads();                 // staging (vmcnt drained) complete

        bf16x8 ah[4], al[4], bh[4], bl[4];
        #pragma unroll
        for (int f = 0; f < 4; ++f) {
            ah[f] = *(const bf16x8*)&AhS[wr + f * 16 + l15][l4 * 8];
            al[f] = *(const bf16x8*)&AlS[wr + f * 16 + l15][l4 * 8];
            bh[f] = *(const bf16x8*)&BhS[wc + f * 16 + l15][l4 * 8];
            bl[f] = *(const bf16x8*)&BlS[wc + f * 16 + l15][l4 * 8];
        }
        #pragma unroll
        for (int i = 0; i < 4; ++i)
            #pragma unroll
            for (int j = 0; j < 4; ++j) {
                acc[i][j] = __builtin_amdgcn_mfma_f32_16x16x32_bf16(ah[i], bh[j], acc[i][j], 0, 0, 0);
                acc[i][j] = __builtin_amdgcn_mfma_f32_16x16x32_bf16(ah[i], bl[j], acc[i][j], 0, 0, 0);
                acc[i][j] = __builtin_amdgcn_mfma_f32_16x16x32_bf16(al[i], bh[j], acc[i][j], 0, 0, 0);
            }
    }

    if (MODE == 0) {
        // per-head LN: wave's 64 cols == one full head (n0%128==0, wc in {0,64})
        const int n_head = (n0 + wc) >> 6;
        float g4[4], b4[4];
        #pragma unroll
        for (int f = 0; f < 4; ++f) {
            g4[f] = gamma[f * 16 + l15];
            b4[f] = beta [f * 16 + l15];
        }
        #pragma unroll
        for (int i = 0; i < 4; ++i)
            #pragma unroll
            for (int j = 0; j < 4; ++j) {
                const float v0 = acc[i][0][j], v1 = acc[i][1][j];
                const float v2 = acc[i][2][j], v3 = acc[i][3][j];
                float s1 = v0 + v1 + v2 + v3;
                float s2 = v0*v0 + v1*v1 + v2*v2 + v3*v3;
                s1 += __shfl_xor(s1, 1); s2 += __shfl_xor(s2, 1);
                s1 += __shfl_xor(s1, 2); s2 += __shfl_xor(s2, 2);
                s1 += __shfl_xor(s1, 4); s2 += __shfl_xor(s2, 4);
                s1 += __shfl_xor(s1, 8); s2 += __shfl_xor(s2, 8);
                const float mu  = s1 * (1.f / 64.f);
                const float var = s2 * (1.f / 64.f) - mu * mu;
                const float rs  = rsqrtf(var + LN_EPS);
                const int m = m0 + wr + i * 16 + l4 * 4 + j;   // m = b*SEQ + t
                const size_t orow =
                    ((size_t)((m >> 11) * NHEADS + n_head) * SEQ + (m & (SEQ - 1))) * HDIM;
                #pragma unroll
                for (int f = 0; f < 4; ++f) {
                    const float y = ((acc[i][f][j] - mu) * rs * g4[f] + b4[f]) * scale;
                    short hi, lo; fsplit(y, hi, lo);
                    OutH[orow + f * 16 + l15] = hi;
                    OutL[orow + f * 16 + l15] = lo;
                }
            }
    } else if (MODE == 1) {
        #pragma unroll
        for (int i = 0; i < 4; ++i)
            #pragma unroll
            for (int j = 0; j < 4; ++j) {
                const int m = m0 + wr + i * 16 + l4 * 4 + j;
                const size_t row = (size_t)m * GN + n0 + wc;
                #pragma unroll
                for (int f = 0; f < 4; ++f) {
                    short hi, lo; fsplit(acc[i][f][j], hi, lo);
                    OutH[row + f * 16 + l15] = hi;
                    OutL[row + f * 16 + l15] = lo;
                }
            }
    } else {
        float b4[4];
        #pragma unroll
        for (int f = 0; f < 4; ++f) b4[f] = bias[n0 + wc + f * 16 + l15];
        #pragma unroll
        for (int i = 0; i < 4; ++i)
            #pragma unroll
            for (int j = 0; j < 4; ++j) {
                const int m = m0 + wr + i * 16 + l4 * 4 + j;
                const size_t row = (size_t)m * GN + n0 + wc;
                #pragma unroll
                for (int f = 0; f < 4; ++f)
                    OutF[row + f * 16 + l15] = acc[i][f][j] + b4[f];
            }
    }
}

// ---------------------------------------------------------------------------
// Split-bf16 V [b][t][h][d] (row-major planes) -> V^T panels [b][h][d][t].
// XOR-swizzled LDS tile to keep the column reads near conflict-free.
// ---------------------------------------------------------------------------
__global__ __launch_bounds__(256)
void conv_v_bf(const short* __restrict__ Vh, const short* __restrict__ Vl,
               short* __restrict__ Th, short* __restrict__ Tl)
{
    __shared__ short Sh[64][72], Sl[64][72];
    const int t  = threadIdx.x;
    const int t0 = blockIdx.x * 64;
    const int hh = blockIdx.y, bb = blockIdx.z;

    #pragma unroll
    for (int p = 0; p < 2; ++p) {
        const int c = t + p * 256;
        const int r = c >> 3, o = c & 7;
        const int oc = (o ^ (r >> 3)) * 8;                 // swizzled col-group
        const size_t ga = ((size_t)(bb * SEQ + t0 + r) * NHEADS + hh) * HDIM + o * 8;
        *(int4v*)&Sh[r][oc] = *(const int4v*)&Vh[ga];
        *(int4v*)&Sl[r][oc] = *(const int4v*)&Vl[ga];
    }
    __syncthreads();

    #pragma unroll
    for (int p = 0; p < 2; ++p) {
        const int c = t + p * 256;
        const int d = c >> 3, tof = (c & 7) * 8;
        const int gsel = d >> 3;
        bf16x8 h8, l8;
        #pragma unroll
        for (int j = 0; j < 8; ++j) {
            const int row = tof + j;
            const int col = ((gsel ^ (row >> 3)) * 8) + (d & 7);
            h8[j] = Sh[row][col];
            l8[j] = Sl[row][col];
        }
        const size_t oa = ((size_t)(bb * NHEADS + hh) * HDIM + d) * SEQ + t0 + tof;
        *(bf16x8*)&Th[oa] = h8;
        *(bf16x8*)&Tl[oa] = l8;
    }
}

// ---------------------------------------------------------------------------
// Causal flash attention, split-bf16 MFMA (unchanged from prior round).
// ---------------------------------------------------------------------------
__global__ __launch_bounds__(256)
void attn_mfma(const short* __restrict__ Qh, const short* __restrict__ Ql,
               const short* __restrict__ Kh, const short* __restrict__ Kl,
               const short* __restrict__ Vh, const short* __restrict__ Vl,
               float* __restrict__ O)
{
    __shared__ short KhS[64][72], KlS[64][72];
    __shared__ short VhS[64][72], VlS[64][72];
    __shared__ short PhS[64][72], PlS[64][72];

    const int t    = threadIdx.x;
    const int lane = t & 63, wv = t >> 6;
    const int l15  = lane & 15, l4 = lane >> 4;
    const int qt   = (int)gridDim.x - 1 - (int)blockIdx.x;   // heavy first
    const int bh   = blockIdx.y;
    const int bb   = bh >> 4, hh = bh & 15;
    const int q0   = qt * 64;
    const int wq0  = wv * 16;

    const size_t kpan = (size_t)bh * SEQ * HDIM;   // [t][d] panels (Q,K)
    const size_t vpan = (size_t)bh * HDIM * SEQ;   // [d][t] panels (V^T)

    bf16x8 qfh[2], qfl[2];
    {
        const size_t qrow = kpan + (size_t)(q0 + wq0 + l15) * HDIM;
        #pragma unroll
        for (int ds = 0; ds < 2; ++ds) {
            qfh[ds] = *(const bf16x8*)&Qh[qrow + l4 * 8 + 32 * ds];
            qfl[ds] = *(const bf16x8*)&Ql[qrow + l4 * 8 + 32 * ds];
        }
    }

    f32x4 oacc[4];
    float m_run[4], l_run[4];
    #pragma unroll
    for (int r = 0; r < 4; ++r) { m_run[r] = -1e30f; l_run[r] = 0.f; }
    #pragma unroll
    for (int nf = 0; nf < 4; ++nf) oacc[nf] = (f32x4){0.f, 0.f, 0.f, 0.f};

    for (int kt = 0; kt <= qt; ++kt) {
        const int k0 = kt * 64;

        __syncthreads();

        #pragma unroll
        for (int p = 0; p < 2; ++p) {
            const int c = t + p * 256;
            const int r = c >> 3, off = (c & 7) * 8;
            *(int4v*)&KhS[r][off] = *(const int4v*)&Kh[kpan + (size_t)(k0 + r) * HDIM + off];
            *(int4v*)&KlS[r][off] = *(const int4v*)&Kl[kpan + (size_t)(k0 + r) * HDIM + off];
            *(int4v*)&VhS[r][off] = *(const int4v*)&Vh[vpan + (size_t)r * SEQ + k0 + off];
            *(int4v*)&VlS[r][off] = *(const int4v*)&Vl[vpan + (size_t)r * SEQ + k0 + off];
        }
        __syncthreads();

        f32x4 s[4];
        #pragma unroll
        for (int nf = 0; nf < 4; ++nf) s[nf] = (f32x4){0.f, 0.f, 0.f, 0.f};

        #pragma unroll
        for (int ds = 0; ds < 2; ++ds) {
            #pragma unroll
            for (int nf = 0; nf < 4; ++nf) {
                const bf16x8 kh = *(const bf16x8*)&KhS[nf * 16 + l15][l4 * 8 + 32 * ds];
                const bf16x8 kl = *(const bf16x8*)&KlS[nf * 16 + l15][l4 * 8 + 32 * ds];
                s[nf] = __builtin_amdgcn_mfma_f32_16x16x32_bf16(qfh[ds], kh, s[nf], 0, 0, 0);
                s[nf] = __builtin_amdgcn_mfma_f32_16x16x32_bf16(qfh[ds], kl, s[nf], 0, 0, 0);
                s[nf] = __builtin_amdgcn_mfma_f32_16x16x32_bf16(qfl[ds], kh, s[nf], 0, 0, 0);
            }
        }

        if (kt == qt) {
            #pragma unroll
            for (int nf = 0; nf < 4; ++nf)
                #pragma unroll
                for (int r = 0; r < 4; ++r) {
                    const int kl_ = nf * 16 + l15;
                    const int ql_ = wq0 + l4 * 4 + r;
                    if (kl_ > ql_) s[nf][r] = -1e30f;
                }
        }

        #pragma unroll
        for (int r = 0; r < 4; ++r) {
            float mx = fmaxf(fmaxf(s[0][r], s[1][r]), fmaxf(s[2][r], s[3][r]));
            mx = fmaxf(mx, __shfl_xor(mx, 1));
            mx = fmaxf(mx, __shfl_xor(mx, 2));
            mx = fmaxf(mx, __shfl_xor(mx, 4));
            mx = fmaxf(mx, __shfl_xor(mx, 8));
            const float mnew = fmaxf(m_run[r], mx);
            const float scf  = __expf(m_run[r] - mnew);
            m_run[r] = mnew;
            float ls = 0.f;
            #pragma unroll
            for (int nf = 0; nf < 4; ++nf) {
                const float p = __expf(s[nf][r] - mnew);
                s[nf][r] = p;
                ls += p;
            }
            ls += __shfl_xor(ls, 1);
            ls += __shfl_xor(ls, 2);
            ls += __shfl_xor(ls, 4);
            ls += __shfl_xor(ls, 8);
            l_run[r] = l_run[r] * scf + ls;
            #pragma unroll
            for (int nf = 0; nf < 4; ++nf) oacc[nf][r] *= scf;
        }

        #pragma unroll
        for (int nf = 0; nf < 4; ++nf)
            #pragma unroll
            for (int r = 0; r < 4; ++r) {
                const float p = s[nf][r];
                const short ph = f2bf(p);
                PhS[wq0 + l4 * 4 + r][nf * 16 + l15] = ph;
                PlS[wq0 + l4 * 4 + r][nf * 16 + l15] = f2bf(p - bf2f(ph));
            }
        asm volatile("s_waitcnt lgkmcnt(0)" ::: "memory");

        #pragma unroll
        for (int ks = 0; ks < 2; ++ks) {
            const bf16x8 pah = *(const bf16x8*)&PhS[wq0 + l15][l4 * 8 + 32 * ks];
            const bf16x8 pal = *(const bf16x8*)&PlS[wq0 + l15][l4 * 8 + 32 * ks];
            #pragma unroll
            for (int nf = 0; nf < 4; ++nf) {
                const bf16x8 vh = *(const bf16x8*)&VhS[nf * 16 + l15][l4 * 8 + 32 * ks];
                const bf16x8 vl = *(const bf16x8*)&VlS[nf * 16 + l15][l4 * 8 + 32 * ks];
                oacc[nf] = __builtin_amdgcn_mfma_f32_16x16x32_bf16(pah, vh, oacc[nf], 0, 0, 0);
                oacc[nf] = __builtin_amdgcn_mfma_f32_16x16x32_bf16(pah, vl, oacc[nf], 0, 0, 0);
                oacc[nf] = __builtin_amdgcn_mfma_f32_16x16x32_bf16(pal, vh, oacc[nf], 0, 0, 0);
            }
        }
    }

    #pragma unroll
    for (int r = 0; r < 4; ++r) {
        const float inv = 1.f / l_run[r];
        const int q = q0 + wq0 + l4 * 4 + r;
        #pragma unroll
        for (int nf = 0; nf < 4; ++nf)
            O[((size_t)(bb * SEQ + q)) * EMB + hh * HDIM + nf * 16 + l15] =
                oacc[nf][r] * inv;
    }
}

// ---------------------------------------------------------------------------
extern "C" void kernel_launch(void* const* d_in, const int* in_sizes, int n_in,
                              void* d_out, int out_size, void* d_ws, size_t ws_size,
                              hipStream_t stream)
{
    const float* x  = (const float*)d_in[0];
    const float* Wk = (const float*)d_in[1];
    const float* Wq = (const float*)d_in[2];
    const float* Wv = (const float*)d_in[3];
    const float* Wu = (const float*)d_in[4];
    const float* bu = (const float*)d_in[5];
    const float* kg = (const float*)d_in[6];
    const float* kb = (const float*)d_in[7];
    const float* qg = (const float*)d_in[8];
    const float* qb = (const float*)d_in[9];
    float* out = (float*)d_out;

    // ws map (52 MB):
    //  [ 0, 8M) Xh -> Vth      [ 8,16M) Xl -> Vtl
    //  [16,24M) Kh -> Oh       [24,32M) Kl -> Ol
    //  [32,40M) Qh             [40,48M) Ql
    //  [48,50M) Wh             [50,52M) Wl
    // d_out doubles as: V split planes (V-GEMM out) -> attn fp32 out -> final out
    char* w = (char*)d_ws;
    short* XhP = (short*)(w);
    short* XlP = (short*)(w + (8u  << 20));
    short* KhP = (short*)(w + (16u << 20));
    short* KlP = (short*)(w + (24u << 20));
    short* QhP = (short*)(w + (32u << 20));
    short* QlP = (short*)(w + (40u << 20));
    short* WhP = (short*)(w + (48u << 20));
    short* WlP = (short*)(w + (50u << 20));
    short* VtmpH = (short*)d_out;
    short* VtmpL = (short*)d_out + (4u << 20);   // +8 MB

    const float inv4 = 0.17677669529663687f;     // 1024^(-1/4)
    const dim3 gg(GN / 128, MROWS / 128);        // (8, 32)

    cvt_split<<<4096, 256, 0, stream>>>(x, XhP, XlP);

    cvt_split<<<1024, 256, 0, stream>>>(Wk, WhP, WlP);
    gemm_mfma<0><<<gg, 256, 0, stream>>>(XhP, XlP, WhP, WlP, kg, kb, inv4,
                                         nullptr, KhP, KlP, nullptr);

    cvt_split<<<1024, 256, 0, stream>>>(Wq, WhP, WlP);
    gemm_mfma<0><<<gg, 256, 0, stream>>>(XhP, XlP, WhP, WlP, qg, qb, inv4,
                                         nullptr, QhP, QlP, nullptr);

    cvt_split<<<1024, 256, 0, stream>>>(Wv, WhP, WlP);
    gemm_mfma<1><<<gg, 256, 0, stream>>>(XhP, XlP, WhP, WlP, nullptr, nullptr,
                                         1.f, nullptr, VtmpH, VtmpL, nullptr);

    conv_v_bf<<<dim3(SEQ / 64, NHEADS, BATCH), 256, 0, stream>>>(VtmpH, VtmpL,
                                                                 XhP, XlP);

    attn_mfma<<<dim3(SEQ / 64, BATCH * NHEADS), 256, 0, stream>>>(
        QhP, QlP, KhP, KlP, XhP, XlP, (float*)d_out);

    cvt_split<<<4096, 256, 0, stream>>>((const float*)d_out, KhP, KlP);

    cvt_split<<<1024, 256, 0, stream>>>(Wu, WhP, WlP);
    gemm_mfma<2><<<gg, 256, 0, stream>>>(KhP, KlP, WhP, WlP, nullptr, nullptr,
                                         1.f, bu, nullptr, nullptr, out);
}

// Round 7
// 379.378 us; speedup vs baseline: 2.9087x; 1.1115x over previous
//
#include <hip/hip_runtime.h>
#include <math.h>

#define EMB 1024
#define NHEADS 16
#define HDIM 64
#define BATCH 2
#define SEQ 2048
#define MROWS (BATCH*SEQ)   /* 4096 */
#define LN_EPS 1e-5f
#define GK 1024
#define GN 1024

typedef __attribute__((ext_vector_type(8))) short bf16x8;
typedef __attribute__((ext_vector_type(4))) short s16x4;
typedef __attribute__((ext_vector_type(4))) float f32x4;
typedef __attribute__((ext_vector_type(4))) int int4v;

__device__ __forceinline__ short f2bf(float f) {     // RNE float->bf16
    union { float f; unsigned u; } v; v.f = f;
    unsigned r = v.u + 0x7FFFu + ((v.u >> 16) & 1u);
    return (short)(r >> 16);
}
__device__ __forceinline__ float bf2f(short s) {
    union { unsigned u; float f; } v; v.u = ((unsigned)(unsigned short)s) << 16;
    return v.f;
}
// truncating split: f = hi + lo + err, |err| <~ 2^-17 |f|
__device__ __forceinline__ void fsplit(float f, short& hi, short& lo) {
    const unsigned u = __float_as_uint(f);
    hi = (short)(u >> 16);
    const float r = f - __uint_as_float(u & 0xFFFF0000u);   // exact
    lo = (short)(__float_as_uint(r) >> 16);
}

__device__ __forceinline__ void gload16(const short* g, short* l) {
    __builtin_amdgcn_global_load_lds(
        (const __attribute__((address_space(1))) unsigned*)g,
        (__attribute__((address_space(3))) unsigned*)l, 16, 0, 0);
}

// ---------------------------------------------------------------------------
// fp32 -> split-bf16 planes (hi, lo). n divisible by 1024.
// ---------------------------------------------------------------------------
__global__ __launch_bounds__(256)
void cvt_split(const float* __restrict__ X, short* __restrict__ H,
               short* __restrict__ L)
{
    const size_t i = (size_t)blockIdx.x * 256 + threadIdx.x;
    const float4 v = *(const float4*)&X[i * 4];
    s16x4 h, l;
    short th, tl;
    fsplit(v.x, th, tl); h[0] = th; l[0] = tl;
    fsplit(v.y, th, tl); h[1] = th; l[1] = tl;
    fsplit(v.z, th, tl); h[2] = th; l[2] = tl;
    fsplit(v.w, th, tl); h[3] = th; l[3] = tl;
    *(s16x4*)&H[i * 4] = h;
    *(s16x4*)&L[i * 4] = l;
}

// ---------------------------------------------------------------------------
// Split-bf16 MFMA GEMM (NT): unchanged from prior round (measured ~45us).
// ---------------------------------------------------------------------------
template<int MODE>
__global__ __launch_bounds__(256)
void gemm_mfma(const short* __restrict__ Ah, const short* __restrict__ Al,
               const short* __restrict__ Bh, const short* __restrict__ Bl,
               const float* __restrict__ gamma, const float* __restrict__ beta,
               float scale, const float* __restrict__ bias,
               short* __restrict__ OutH, short* __restrict__ OutL,
               float* __restrict__ OutF)
{
    __shared__ short AhS[128][32], AlS[128][32], BhS[128][32], BlS[128][32];

    const int t   = threadIdx.x;
    const int ln  = t & 63, wv = t >> 6;
    const int l15 = ln & 15, l4 = ln >> 4;
    const int m0  = blockIdx.y * 128;
    const int n0  = blockIdx.x * 128;
    const int wr  = (wv >> 1) * 64, wc = (wv & 1) * 64;

    const short* gplane = (wv == 0) ? Ah : (wv == 1) ? Al : (wv == 2) ? Bh : Bl;
    const int    grow0  = (wv < 2) ? m0 : n0;
    short* lplane = (wv == 0) ? &AhS[0][0] : (wv == 1) ? &AlS[0][0]
                  : (wv == 2) ? &BhS[0][0] : &BlS[0][0];

    f32x4 acc[4][4];
    #pragma unroll
    for (int i = 0; i < 4; ++i)
        #pragma unroll
        for (int j = 0; j < 4; ++j) acc[i][j] = (f32x4){0.f, 0.f, 0.f, 0.f};

    for (int k0 = 0; k0 < GK; k0 += 32) {
        __syncthreads();
        #pragma unroll
        for (int s = 0; s < 8; ++s) {
            const int chunk = s * 64 + ln;
            const int r = chunk >> 2, c = chunk & 3;
            gload16(gplane + (size_t)(grow0 + r) * GK + k0 + c * 8,
                    lplane + s * 512);
        }
        __syncthreads();

        bf16x8 ah[4], al[4], bh[4], bl[4];
        #pragma unroll
        for (int f = 0; f < 4; ++f) {
            ah[f] = *(const bf16x8*)&AhS[wr + f * 16 + l15][l4 * 8];
            al[f] = *(const bf16x8*)&AlS[wr + f * 16 + l15][l4 * 8];
            bh[f] = *(const bf16x8*)&BhS[wc + f * 16 + l15][l4 * 8];
            bl[f] = *(const bf16x8*)&BlS[wc + f * 16 + l15][l4 * 8];
        }
        #pragma unroll
        for (int i = 0; i < 4; ++i)
            #pragma unroll
            for (int j = 0; j < 4; ++j) {
                acc[i][j] = __builtin_amdgcn_mfma_f32_16x16x32_bf16(ah[i], bh[j], acc[i][j], 0, 0, 0);
                acc[i][j] = __builtin_amdgcn_mfma_f32_16x16x32_bf16(ah[i], bl[j], acc[i][j], 0, 0, 0);
                acc[i][j] = __builtin_amdgcn_mfma_f32_16x16x32_bf16(al[i], bh[j], acc[i][j], 0, 0, 0);
            }
    }

    if (MODE == 0) {
        const int n_head = (n0 + wc) >> 6;
        float g4[4], b4[4];
        #pragma unroll
        for (int f = 0; f < 4; ++f) {
            g4[f] = gamma[f * 16 + l15];
            b4[f] = beta [f * 16 + l15];
        }
        #pragma unroll
        for (int i = 0; i < 4; ++i)
            #pragma unroll
            for (int j = 0; j < 4; ++j) {
                const float v0 = acc[i][0][j], v1 = acc[i][1][j];
                const float v2 = acc[i][2][j], v3 = acc[i][3][j];
                float s1 = v0 + v1 + v2 + v3;
                float s2 = v0*v0 + v1*v1 + v2*v2 + v3*v3;
                s1 += __shfl_xor(s1, 1); s2 += __shfl_xor(s2, 1);
                s1 += __shfl_xor(s1, 2); s2 += __shfl_xor(s2, 2);
                s1 += __shfl_xor(s1, 4); s2 += __shfl_xor(s2, 4);
                s1 += __shfl_xor(s1, 8); s2 += __shfl_xor(s2, 8);
                const float mu  = s1 * (1.f / 64.f);
                const float var = s2 * (1.f / 64.f) - mu * mu;
                const float rs  = rsqrtf(var + LN_EPS);
                const int m = m0 + wr + i * 16 + l4 * 4 + j;   // m = b*SEQ + t
                const size_t orow =
                    ((size_t)((m >> 11) * NHEADS + n_head) * SEQ + (m & (SEQ - 1))) * HDIM;
                #pragma unroll
                for (int f = 0; f < 4; ++f) {
                    const float y = ((acc[i][f][j] - mu) * rs * g4[f] + b4[f]) * scale;
                    short hi, lo; fsplit(y, hi, lo);
                    OutH[orow + f * 16 + l15] = hi;
                    OutL[orow + f * 16 + l15] = lo;
                }
            }
    } else if (MODE == 1) {
        #pragma unroll
        for (int i = 0; i < 4; ++i)
            #pragma unroll
            for (int j = 0; j < 4; ++j) {
                const int m = m0 + wr + i * 16 + l4 * 4 + j;
                const size_t row = (size_t)m * GN + n0 + wc;
                #pragma unroll
                for (int f = 0; f < 4; ++f) {
                    short hi, lo; fsplit(acc[i][f][j], hi, lo);
                    OutH[row + f * 16 + l15] = hi;
                    OutL[row + f * 16 + l15] = lo;
                }
            }
    } else {
        float b4[4];
        #pragma unroll
        for (int f = 0; f < 4; ++f) b4[f] = bias[n0 + wc + f * 16 + l15];
        #pragma unroll
        for (int i = 0; i < 4; ++i)
            #pragma unroll
            for (int j = 0; j < 4; ++j) {
                const int m = m0 + wr + i * 16 + l4 * 4 + j;
                const size_t row = (size_t)m * GN + n0 + wc;
                #pragma unroll
                for (int f = 0; f < 4; ++f)
                    OutF[row + f * 16 + l15] = acc[i][f][j] + b4[f];
            }
    }
}

// ---------------------------------------------------------------------------
// Split-bf16 V [b][t][h][d] (row-major planes) -> V^T panels [b][h][d][t].
// ---------------------------------------------------------------------------
__global__ __launch_bounds__(256)
void conv_v_bf(const short* __restrict__ Vh, const short* __restrict__ Vl,
               short* __restrict__ Th, short* __restrict__ Tl)
{
    __shared__ short Sh[64][72], Sl[64][72];
    const int t  = threadIdx.x;
    const int t0 = blockIdx.x * 64;
    const int hh = blockIdx.y, bb = blockIdx.z;

    #pragma unroll
    for (int p = 0; p < 2; ++p) {
        const int c = t + p * 256;
        const int r = c >> 3, o = c & 7;
        const int oc = (o ^ (r >> 3)) * 8;                 // swizzled col-group
        const size_t ga = ((size_t)(bb * SEQ + t0 + r) * NHEADS + hh) * HDIM + o * 8;
        *(int4v*)&Sh[r][oc] = *(const int4v*)&Vh[ga];
        *(int4v*)&Sl[r][oc] = *(const int4v*)&Vl[ga];
    }
    __syncthreads();

    #pragma unroll
    for (int p = 0; p < 2; ++p) {
        const int c = t + p * 256;
        const int d = c >> 3, tof = (c & 7) * 8;
        const int gsel = d >> 3;
        bf16x8 h8, l8;
        #pragma unroll
        for (int j = 0; j < 8; ++j) {
            const int row = tof + j;
            const int col = ((gsel ^ (row >> 3)) * 8) + (d & 7);
            h8[j] = Sh[row][col];
            l8[j] = Sl[row][col];
        }
        const size_t oa = ((size_t)(bb * NHEADS + hh) * HDIM + d) * SEQ + t0 + tof;
        *(bf16x8*)&Th[oa] = h8;
        *(bf16x8*)&Tl[oa] = l8;
    }
}

// ---------------------------------------------------------------------------
// Causal flash attention, split-bf16 MFMA.
// QBLK=128 (8 waves x 16-q stripe), KVBLK=64. T14 reg-prefetch staging:
// next tile's K/V loaded to regs during current tile's compute; ds_write
// after the loop-top barrier. Per-wave dead-tile skip on the causal edge.
// LDS: K/V 4x[64][72] + P 2x[128][72] = 73.7KB -> 2 blocks/CU (16 waves).
// ---------------------------------------------------------------------------
__global__ __launch_bounds__(512, 4)
void attn_mfma(const short* __restrict__ Qh, const short* __restrict__ Ql,
               const short* __restrict__ Kh, const short* __restrict__ Kl,
               const short* __restrict__ Vh, const short* __restrict__ Vl,
               float* __restrict__ O)
{
    __shared__ short KhS[64][72], KlS[64][72];
    __shared__ short VhS[64][72], VlS[64][72];
    __shared__ short PhS[128][72], PlS[128][72];

    const int t    = threadIdx.x;
    const int lane = t & 63, wv = t >> 6;            // 8 waves
    const int l15  = lane & 15, l4 = lane >> 4;
    const int qt   = (int)gridDim.x - 1 - (int)blockIdx.x;   // heavy first
    const int bh   = blockIdx.y;
    const int bb   = bh >> 4, hh = bh & 15;
    const int q0   = qt * 128;
    const int wq0  = wv * 16;

    const size_t kpan = (size_t)bh * SEQ * HDIM;   // [t][d] panels (Q,K)
    const size_t vpan = (size_t)bh * HDIM * SEQ;   // [d][t] panels (V^T)

    // staging role: 1 x 16B chunk per plane per thread (64x64 shorts/plane)
    const int sr   = t >> 3;          // 0..63
    const int soff = (t & 7) * 8;     // 0..56

    bf16x8 qfh[2], qfl[2];
    {
        const size_t qrow = kpan + (size_t)(q0 + wq0 + l15) * HDIM;
        #pragma unroll
        for (int ds = 0; ds < 2; ++ds) {
            qfh[ds] = *(const bf16x8*)&Qh[qrow + l4 * 8 + 32 * ds];
            qfl[ds] = *(const bf16x8*)&Ql[qrow + l4 * 8 + 32 * ds];
        }
    }

    f32x4 oacc[4];
    float m_run[4], l_run[4];
    #pragma unroll
    for (int r = 0; r < 4; ++r) { m_run[r] = -1e30f; l_run[r] = 0.f; }
    #pragma unroll
    for (int nf = 0; nf < 4; ++nf) oacc[nf] = (f32x4){0.f, 0.f, 0.f, 0.f};

    const int NT = 2 * qt + 2;

    // prefetch tile 0 into regs
    int4v pKh, pKl, pVh, pVl;
    {
        pKh = *(const int4v*)&Kh[kpan + (size_t)sr * HDIM + soff];
        pKl = *(const int4v*)&Kl[kpan + (size_t)sr * HDIM + soff];
        pVh = *(const int4v*)&Vh[vpan + (size_t)sr * SEQ + soff];
        pVl = *(const int4v*)&Vl[vpan + (size_t)sr * SEQ + soff];
    }

    for (int kt = 0; kt < NT; ++kt) {
        const int k0 = kt * 64;

        __syncthreads();   // all waves done reading prev tile's LDS

        *(int4v*)&KhS[sr][soff] = pKh;
        *(int4v*)&KlS[sr][soff] = pKl;
        *(int4v*)&VhS[sr][soff] = pVh;
        *(int4v*)&VlS[sr][soff] = pVl;

        if (kt + 1 < NT) {             // issue next tile's loads (hide under compute)
            const int kn = k0 + 64;
            pKh = *(const int4v*)&Kh[kpan + (size_t)(kn + sr) * HDIM + soff];
            pKl = *(const int4v*)&Kl[kpan + (size_t)(kn + sr) * HDIM + soff];
            pVh = *(const int4v*)&Vh[vpan + (size_t)sr * SEQ + kn + soff];
            pVl = *(const int4v*)&Vl[vpan + (size_t)sr * SEQ + kn + soff];
        }
        __syncthreads();   // current tile's LDS ready

        if (k0 > q0 + wq0 + 15) continue;   // tile entirely future for this wave

        // ---- QK^T: 16q x 64k stripe ----
        f32x4 s[4];
        #pragma unroll
        for (int nf = 0; nf < 4; ++nf) s[nf] = (f32x4){0.f, 0.f, 0.f, 0.f};

        #pragma unroll
        for (int ds = 0; ds < 2; ++ds) {
            #pragma unroll
            for (int nf = 0; nf < 4; ++nf) {
                const bf16x8 kh = *(const bf16x8*)&KhS[nf * 16 + l15][l4 * 8 + 32 * ds];
                const bf16x8 kl = *(const bf16x8*)&KlS[nf * 16 + l15][l4 * 8 + 32 * ds];
                s[nf] = __builtin_amdgcn_mfma_f32_16x16x32_bf16(qfh[ds], kh, s[nf], 0, 0, 0);
                s[nf] = __builtin_amdgcn_mfma_f32_16x16x32_bf16(qfh[ds], kl, s[nf], 0, 0, 0);
                s[nf] = __builtin_amdgcn_mfma_f32_16x16x32_bf16(qfl[ds], kh, s[nf], 0, 0, 0);
            }
        }

        if (k0 + 63 > q0 + wq0) {      // causal mask (diag kept)
            #pragma unroll
            for (int nf = 0; nf < 4; ++nf)
                #pragma unroll
                for (int r = 0; r < 4; ++r) {
                    const int kg = k0 + nf * 16 + l15;
                    const int qg = q0 + wq0 + l4 * 4 + r;
                    if (kg > qg) s[nf][r] = -1e30f;
                }
        }

        // ---- online softmax in fragment registers ----
        #pragma unroll
        for (int r = 0; r < 4; ++r) {
            float mx = fmaxf(fmaxf(s[0][r], s[1][r]), fmaxf(s[2][r], s[3][r]));
            mx = fmaxf(mx, __shfl_xor(mx, 1));
            mx = fmaxf(mx, __shfl_xor(mx, 2));
            mx = fmaxf(mx, __shfl_xor(mx, 4));
            mx = fmaxf(mx, __shfl_xor(mx, 8));
            const float mnew = fmaxf(m_run[r], mx);
            const float scf  = __expf(m_run[r] - mnew);
            m_run[r] = mnew;
            float ls = 0.f;
            #pragma unroll
            for (int nf = 0; nf < 4; ++nf) {
                const float p = __expf(s[nf][r] - mnew);
                s[nf][r] = p;
                ls += p;
            }
            ls += __shfl_xor(ls, 1);
            ls += __shfl_xor(ls, 2);
            ls += __shfl_xor(ls, 4);
            ls += __shfl_xor(ls, 8);
            l_run[r] = l_run[r] * scf + ls;
            #pragma unroll
            for (int nf = 0; nf < 4; ++nf) oacc[nf][r] *= scf;
        }

        // ---- P -> wave-private LDS (reshape C-frag -> A-frag) ----
        #pragma unroll
        for (int nf = 0; nf < 4; ++nf)
            #pragma unroll
            for (int r = 0; r < 4; ++r) {
                const float p = s[nf][r];
                const short ph = f2bf(p);
                PhS[wq0 + l4 * 4 + r][nf * 16 + l15] = ph;
                PlS[wq0 + l4 * 4 + r][nf * 16 + l15] = f2bf(p - bf2f(ph));
            }
        asm volatile("s_waitcnt lgkmcnt(0)" ::: "memory");  // wave-local P ready

        // ---- PV: oacc += P @ V^T ----
        #pragma unroll
        for (int ks = 0; ks < 2; ++ks) {
            const bf16x8 pah = *(const bf16x8*)&PhS[wq0 + l15][l4 * 8 + 32 * ks];
            const bf16x8 pal = *(const bf16x8*)&PlS[wq0 + l15][l4 * 8 + 32 * ks];
            #pragma unroll
            for (int nf = 0; nf < 4; ++nf) {
                const bf16x8 vh = *(const bf16x8*)&VhS[nf * 16 + l15][l4 * 8 + 32 * ks];
                const bf16x8 vl = *(const bf16x8*)&VlS[nf * 16 + l15][l4 * 8 + 32 * ks];
                oacc[nf] = __builtin_amdgcn_mfma_f32_16x16x32_bf16(pah, vh, oacc[nf], 0, 0, 0);
                oacc[nf] = __builtin_amdgcn_mfma_f32_16x16x32_bf16(pah, vl, oacc[nf], 0, 0, 0);
                oacc[nf] = __builtin_amdgcn_mfma_f32_16x16x32_bf16(pal, vh, oacc[nf], 0, 0, 0);
            }
        }
    }

    // epilogue: normalize, write O fp32 [b][t][h*64+d]
    #pragma unroll
    for (int r = 0; r < 4; ++r) {
        const float inv = 1.f / l_run[r];
        const int q = q0 + wq0 + l4 * 4 + r;
        #pragma unroll
        for (int nf = 0; nf < 4; ++nf)
            O[((size_t)(bb * SEQ + q)) * EMB + hh * HDIM + nf * 16 + l15] =
                oacc[nf][r] * inv;
    }
}

// ---------------------------------------------------------------------------
extern "C" void kernel_launch(void* const* d_in, const int* in_sizes, int n_in,
                              void* d_out, int out_size, void* d_ws, size_t ws_size,
                              hipStream_t stream)
{
    const float* x  = (const float*)d_in[0];
    const float* Wk = (const float*)d_in[1];
    const float* Wq = (const float*)d_in[2];
    const float* Wv = (const float*)d_in[3];
    const float* Wu = (const float*)d_in[4];
    const float* bu = (const float*)d_in[5];
    const float* kg = (const float*)d_in[6];
    const float* kb = (const float*)d_in[7];
    const float* qg = (const float*)d_in[8];
    const float* qb = (const float*)d_in[9];
    float* out = (float*)d_out;

    // ws map (52 MB):
    //  [ 0, 8M) Xh -> Vth      [ 8,16M) Xl -> Vtl
    //  [16,24M) Kh -> Oh       [24,32M) Kl -> Ol
    //  [32,40M) Qh             [40,48M) Ql
    //  [48,50M) Wh             [50,52M) Wl
    // d_out doubles as: V split planes (V-GEMM out) -> attn fp32 out -> final out
    char* w = (char*)d_ws;
    short* XhP = (short*)(w);
    short* XlP = (short*)(w + (8u  << 20));
    short* KhP = (short*)(w + (16u << 20));
    short* KlP = (short*)(w + (24u << 20));
    short* QhP = (short*)(w + (32u << 20));
    short* QlP = (short*)(w + (40u << 20));
    short* WhP = (short*)(w + (48u << 20));
    short* WlP = (short*)(w + (50u << 20));
    short* VtmpH = (short*)d_out;
    short* VtmpL = (short*)d_out + (4u << 20);   // +8 MB

    const float inv4 = 0.17677669529663687f;     // 1024^(-1/4)
    const dim3 gg(GN / 128, MROWS / 128);        // (8, 32)

    cvt_split<<<4096, 256, 0, stream>>>(x, XhP, XlP);

    cvt_split<<<1024, 256, 0, stream>>>(Wk, WhP, WlP);
    gemm_mfma<0><<<gg, 256, 0, stream>>>(XhP, XlP, WhP, WlP, kg, kb, inv4,
                                         nullptr, KhP, KlP, nullptr);

    cvt_split<<<1024, 256, 0, stream>>>(Wq, WhP, WlP);
    gemm_mfma<0><<<gg, 256, 0, stream>>>(XhP, XlP, WhP, WlP, qg, qb, inv4,
                                         nullptr, QhP, QlP, nullptr);

    cvt_split<<<1024, 256, 0, stream>>>(Wv, WhP, WlP);
    gemm_mfma<1><<<gg, 256, 0, stream>>>(XhP, XlP, WhP, WlP, nullptr, nullptr,
                                         1.f, nullptr, VtmpH, VtmpL, nullptr);

    conv_v_bf<<<dim3(SEQ / 64, NHEADS, BATCH), 256, 0, stream>>>(VtmpH, VtmpL,
                                                                 XhP, XlP);

    attn_mfma<<<dim3(SEQ / 128, BATCH * NHEADS), 512, 0, stream>>>(
        QhP, QlP, KhP, KlP, XhP, XlP, (float*)d_out);

    cvt_split<<<4096, 256, 0, stream>>>((const float*)d_out, KhP, KlP);

    cvt_split<<<1024, 256, 0, stream>>>(Wu, WhP, WlP);
    gemm_mfma<2><<<gg, 256, 0, stream>>>(KhP, KlP, WhP, WlP, nullptr, nullptr,
                                         1.f, bu, nullptr, nullptr, out);
}

// Round 8
// 295.248 us; speedup vs baseline: 3.7375x; 1.2849x over previous
//
#include <hip/hip_runtime.h>
#include <math.h>

#define EMB 1024
#define NHEADS 16
#define HDIM 64
#define BATCH 2
#define SEQ 2048
#define MROWS (BATCH*SEQ)   /* 4096 */
#define LN_EPS 1e-5f
#define GK 1024
#define GN 1024

typedef __attribute__((ext_vector_type(8))) short bf16x8;
typedef __attribute__((ext_vector_type(4))) short s16x4;
typedef __attribute__((ext_vector_type(4))) float f32x4;
typedef __attribute__((ext_vector_type(4))) int int4v;

__device__ __forceinline__ short f2bf(float f) {     // RNE float->bf16
    union { float f; unsigned u; } v; v.f = f;
    unsigned r = v.u + 0x7FFFu + ((v.u >> 16) & 1u);
    return (short)(r >> 16);
}
__device__ __forceinline__ float bf2f(short s) {
    union { unsigned u; float f; } v; v.u = ((unsigned)(unsigned short)s) << 16;
    return v.f;
}
// truncating split: f = hi + lo + err, |err| <~ 2^-17 |f|
__device__ __forceinline__ void fsplit(float f, short& hi, short& lo) {
    const unsigned u = __float_as_uint(f);
    hi = (short)(u >> 16);
    const float r = f - __uint_as_float(u & 0xFFFF0000u);   // exact
    lo = (short)(__float_as_uint(r) >> 16);
}

__device__ __forceinline__ void gload16(const short* g, short* l) {
    __builtin_amdgcn_global_load_lds(
        (const __attribute__((address_space(1))) unsigned*)g,
        (__attribute__((address_space(3))) unsigned*)l, 16, 0, 0);
}

// ---------------------------------------------------------------------------
// fp32 -> split-bf16 planes. x input (16.8M elems).
// ---------------------------------------------------------------------------
__global__ __launch_bounds__(256)
void cvt_split(const float* __restrict__ X, short* __restrict__ H,
               short* __restrict__ L)
{
    const size_t i = (size_t)blockIdx.x * 256 + threadIdx.x;
    const float4 v = *(const float4*)&X[i * 4];
    s16x4 h, l;
    short th, tl;
    fsplit(v.x, th, tl); h[0] = th; l[0] = tl;
    fsplit(v.y, th, tl); h[1] = th; l[1] = tl;
    fsplit(v.z, th, tl); h[2] = th; l[2] = tl;
    fsplit(v.w, th, tl); h[3] = th; l[3] = tl;
    *(s16x4*)&H[i * 4] = h;
    *(s16x4*)&L[i * 4] = l;
}

// all four weights -> 4 slots of (1M shorts) in H/L planes. grid (1024, 4)
__global__ __launch_bounds__(256)
void cvt_w4(const float* __restrict__ W0, const float* __restrict__ W1,
            const float* __restrict__ W2, const float* __restrict__ W3,
            short* __restrict__ H, short* __restrict__ L)
{
    const int z = blockIdx.y;
    const float* W = (z == 0) ? W0 : (z == 1) ? W1 : (z == 2) ? W2 : W3;
    const size_t i = (size_t)blockIdx.x * 256 + threadIdx.x;
    const size_t o = ((size_t)z << 20) + i * 4;
    const float4 v = *(const float4*)&W[i * 4];
    s16x4 h, l;
    short th, tl;
    fsplit(v.x, th, tl); h[0] = th; l[0] = tl;
    fsplit(v.y, th, tl); h[1] = th; l[1] = tl;
    fsplit(v.z, th, tl); h[2] = th; l[2] = tl;
    fsplit(v.w, th, tl); h[3] = th; l[3] = tl;
    *(s16x4*)&H[o] = h;
    *(s16x4*)&L[o] = l;
}

// ---------------------------------------------------------------------------
// Fused K/Q/V split-bf16 MFMA GEMM. blockIdx.z selects weight slot + epilogue:
//   z=0: LN(kg,kb)*inv4 -> K split panels [b][h][t][d]
//   z=1: LN(qg,qb)*inv4 -> Q split panels
//   z=2: direct V^T split panels [b][h][d][t]
// 128x128 tile, BK=32, 4 waves (2x2, 64x64/wave), 3 MFMAs per frag pair.
// grid (8, 32, 3) = 768 blocks -> 3 blocks/CU.
// ---------------------------------------------------------------------------
__global__ __launch_bounds__(256, 3)
void gemm_kqv(const short* __restrict__ Xh, const short* __restrict__ Xl,
              const short* __restrict__ W4h, const short* __restrict__ W4l,
              const float* __restrict__ kg, const float* __restrict__ kb,
              const float* __restrict__ qg, const float* __restrict__ qb,
              float scale,
              short* __restrict__ KhP, short* __restrict__ KlP,
              short* __restrict__ QhP, short* __restrict__ QlP,
              short* __restrict__ VTh, short* __restrict__ VTl)
{
    __shared__ short AhS[128][32], AlS[128][32], BhS[128][32], BlS[128][32];

    const int t   = threadIdx.x;
    const int ln  = t & 63, wv = t >> 6;
    const int l15 = ln & 15, l4 = ln >> 4;
    const int m0  = blockIdx.y * 128;
    const int n0  = blockIdx.x * 128;
    const int z   = blockIdx.z;
    const int wr  = (wv >> 1) * 64, wc = (wv & 1) * 64;

    const short* Bh = W4h + ((size_t)z << 20);
    const short* Bl = W4l + ((size_t)z << 20);

    const short* gplane = (wv == 0) ? Xh : (wv == 1) ? Xl : (wv == 2) ? Bh : Bl;
    const int    grow0  = (wv < 2) ? m0 : n0;
    short* lplane = (wv == 0) ? &AhS[0][0] : (wv == 1) ? &AlS[0][0]
                  : (wv == 2) ? &BhS[0][0] : &BlS[0][0];

    f32x4 acc[4][4];
    #pragma unroll
    for (int i = 0; i < 4; ++i)
        #pragma unroll
        for (int j = 0; j < 4; ++j) acc[i][j] = (f32x4){0.f, 0.f, 0.f, 0.f};

    for (int k0 = 0; k0 < GK; k0 += 32) {
        __syncthreads();
        #pragma unroll
        for (int s = 0; s < 8; ++s) {
            const int chunk = s * 64 + ln;
            const int r = chunk >> 2, c = chunk & 3;
            gload16(gplane + (size_t)(grow0 + r) * GK + k0 + c * 8,
                    lplane + s * 512);
        }
        __syncthreads();

        bf16x8 ah[4], al[4], bh[4], bl[4];
        #pragma unroll
        for (int f = 0; f < 4; ++f) {
            ah[f] = *(const bf16x8*)&AhS[wr + f * 16 + l15][l4 * 8];
            al[f] = *(const bf16x8*)&AlS[wr + f * 16 + l15][l4 * 8];
            bh[f] = *(const bf16x8*)&BhS[wc + f * 16 + l15][l4 * 8];
            bl[f] = *(const bf16x8*)&BlS[wc + f * 16 + l15][l4 * 8];
        }
        #pragma unroll
        for (int i = 0; i < 4; ++i)
            #pragma unroll
            for (int j = 0; j < 4; ++j) {
                acc[i][j] = __builtin_amdgcn_mfma_f32_16x16x32_bf16(ah[i], bh[j], acc[i][j], 0, 0, 0);
                acc[i][j] = __builtin_amdgcn_mfma_f32_16x16x32_bf16(ah[i], bl[j], acc[i][j], 0, 0, 0);
                acc[i][j] = __builtin_amdgcn_mfma_f32_16x16x32_bf16(al[i], bh[j], acc[i][j], 0, 0, 0);
            }
    }

    if (z < 2) {
        // per-head LN epilogue -> [b][h][t][d] split panels
        const float* gamma = (z == 0) ? kg : qg;
        const float* beta  = (z == 0) ? kb : qb;
        short* OutH = (z == 0) ? KhP : QhP;
        short* OutL = (z == 0) ? KlP : QlP;
        const int n_head = (n0 + wc) >> 6;
        float g4[4], b4[4];
        #pragma unroll
        for (int f = 0; f < 4; ++f) {
            g4[f] = gamma[f * 16 + l15];
            b4[f] = beta [f * 16 + l15];
        }
        #pragma unroll
        for (int i = 0; i < 4; ++i)
            #pragma unroll
            for (int j = 0; j < 4; ++j) {
                const float v0 = acc[i][0][j], v1 = acc[i][1][j];
                const float v2 = acc[i][2][j], v3 = acc[i][3][j];
                float s1 = v0 + v1 + v2 + v3;
                float s2 = v0*v0 + v1*v1 + v2*v2 + v3*v3;
                s1 += __shfl_xor(s1, 1); s2 += __shfl_xor(s2, 1);
                s1 += __shfl_xor(s1, 2); s2 += __shfl_xor(s2, 2);
                s1 += __shfl_xor(s1, 4); s2 += __shfl_xor(s2, 4);
                s1 += __shfl_xor(s1, 8); s2 += __shfl_xor(s2, 8);
                const float mu  = s1 * (1.f / 64.f);
                const float var = s2 * (1.f / 64.f) - mu * mu;
                const float rs  = rsqrtf(var + LN_EPS);
                const int m = m0 + wr + i * 16 + l4 * 4 + j;   // m = b*SEQ + t
                const size_t orow =
                    ((size_t)((m >> 11) * NHEADS + n_head) * SEQ + (m & (SEQ - 1))) * HDIM;
                #pragma unroll
                for (int f = 0; f < 4; ++f) {
                    const float y = ((acc[i][f][j] - mu) * rs * g4[f] + b4[f]) * scale;
                    short hi, lo; fsplit(y, hi, lo);
                    OutH[orow + f * 16 + l15] = hi;
                    OutL[orow + f * 16 + l15] = lo;
                }
            }
    } else {
        // V^T epilogue: [b][h][d][t] split panels, 8B stores (4 consecutive t)
        #pragma unroll
        for (int i = 0; i < 4; ++i)
            #pragma unroll
            for (int f = 0; f < 4; ++f) {
                s16x4 h4, l4v;
                #pragma unroll
                for (int j = 0; j < 4; ++j) {
                    short hi, lo; fsplit(acc[i][f][j], hi, lo);
                    h4[j] = hi; l4v[j] = lo;
                }
                const int n  = n0 + wc + f * 16 + l15;
                const int hh = n >> 6, dd = n & 63;
                const int mb = m0 + wr + i * 16 + l4 * 4;      // j=0 row
                const size_t oa =
                    (((size_t)((mb >> 11) * NHEADS + hh)) * HDIM + dd) * SEQ + (mb & (SEQ - 1));
                *(s16x4*)&VTh[oa] = h4;
                *(s16x4*)&VTl[oa] = l4v;
            }
    }
}

// ---------------------------------------------------------------------------
// Final GEMM: out = A@Wu^T + bias, fp32 out. BM=64 tile (wave=32x64),
// grid (8, 64) = 512 blocks -> 2 blocks/CU.
// ---------------------------------------------------------------------------
__global__ __launch_bounds__(256, 2)
void gemm_out(const short* __restrict__ Ah, const short* __restrict__ Al,
              const short* __restrict__ Bh, const short* __restrict__ Bl,
              const float* __restrict__ bias, float* __restrict__ OutF)
{
    __shared__ short AhS[64][32], AlS[64][32], BhS[128][32], BlS[128][32];

    const int t   = threadIdx.x;
    const int ln  = t & 63, wv = t >> 6;
    const int l15 = ln & 15, l4 = ln >> 4;
    const int m0  = blockIdx.y * 64;
    const int n0  = blockIdx.x * 128;
    const int wr  = (wv >> 1) * 32, wc = (wv & 1) * 64;

    const short* gplane = (wv == 0) ? Ah : (wv == 1) ? Al : (wv == 2) ? Bh : Bl;
    const int    grow0  = (wv < 2) ? m0 : n0;
    const int    nseg   = (wv < 2) ? 4 : 8;
    short* lplane = (wv == 0) ? &AhS[0][0] : (wv == 1) ? &AlS[0][0]
                  : (wv == 2) ? &BhS[0][0] : &BlS[0][0];

    f32x4 acc[2][4];
    #pragma unroll
    for (int i = 0; i < 2; ++i)
        #pragma unroll
        for (int j = 0; j < 4; ++j) acc[i][j] = (f32x4){0.f, 0.f, 0.f, 0.f};

    for (int k0 = 0; k0 < GK; k0 += 32) {
        __syncthreads();
        for (int s = 0; s < nseg; ++s) {
            const int chunk = s * 64 + ln;
            const int r = chunk >> 2, c = chunk & 3;
            gload16(gplane + (size_t)(grow0 + r) * GK + k0 + c * 8,
                    lplane + s * 512);
        }
        __syncthreads();

        bf16x8 ah[2], al[2], bh[4], bl[4];
        #pragma unroll
        for (int f = 0; f < 2; ++f) {
            ah[f] = *(const bf16x8*)&AhS[wr + f * 16 + l15][l4 * 8];
            al[f] = *(const bf16x8*)&AlS[wr + f * 16 + l15][l4 * 8];
        }
        #pragma unroll
        for (int f = 0; f < 4; ++f) {
            bh[f] = *(const bf16x8*)&BhS[wc + f * 16 + l15][l4 * 8];
            bl[f] = *(const bf16x8*)&BlS[wc + f * 16 + l15][l4 * 8];
        }
        #pragma unroll
        for (int i = 0; i < 2; ++i)
            #pragma unroll
            for (int j = 0; j < 4; ++j) {
                acc[i][j] = __builtin_amdgcn_mfma_f32_16x16x32_bf16(ah[i], bh[j], acc[i][j], 0, 0, 0);
                acc[i][j] = __builtin_amdgcn_mfma_f32_16x16x32_bf16(ah[i], bl[j], acc[i][j], 0, 0, 0);
                acc[i][j] = __builtin_amdgcn_mfma_f32_16x16x32_bf16(al[i], bh[j], acc[i][j], 0, 0, 0);
            }
    }

    float b4[4];
    #pragma unroll
    for (int f = 0; f < 4; ++f) b4[f] = bias[n0 + wc + f * 16 + l15];
    #pragma unroll
    for (int i = 0; i < 2; ++i)
        #pragma unroll
        for (int j = 0; j < 4; ++j) {
            const int m = m0 + wr + i * 16 + l4 * 4 + j;
            const size_t row = (size_t)m * GN + n0 + wc;
            #pragma unroll
            for (int f = 0; f < 4; ++f)
                OutF[row + f * 16 + l15] = acc[i][f][j] + b4[f];
        }
}

// ---------------------------------------------------------------------------
// Causal flash attention, split-bf16 MFMA (structure unchanged from R7;
// epilogue now emits split planes directly — same fsplit values as the old
// fp32 + cvt_split path, so numerics identical).
// ---------------------------------------------------------------------------
__global__ __launch_bounds__(512, 4)
void attn_mfma(const short* __restrict__ Qh, const short* __restrict__ Ql,
               const short* __restrict__ Kh, const short* __restrict__ Kl,
               const short* __restrict__ Vh, const short* __restrict__ Vl,
               short* __restrict__ Oh, short* __restrict__ Ol)
{
    __shared__ short KhS[64][72], KlS[64][72];
    __shared__ short VhS[64][72], VlS[64][72];
    __shared__ short PhS[128][72], PlS[128][72];

    const int t    = threadIdx.x;
    const int lane = t & 63, wv = t >> 6;            // 8 waves
    const int l15  = lane & 15, l4 = lane >> 4;
    const int qt   = (int)gridDim.x - 1 - (int)blockIdx.x;   // heavy first
    const int bh   = blockIdx.y;
    const int bb   = bh >> 4, hh = bh & 15;
    const int q0   = qt * 128;
    const int wq0  = wv * 16;

    const size_t kpan = (size_t)bh * SEQ * HDIM;   // [t][d] panels (Q,K)
    const size_t vpan = (size_t)bh * HDIM * SEQ;   // [d][t] panels (V^T)

    const int sr   = t >> 3;          // 0..63
    const int soff = (t & 7) * 8;     // 0..56

    bf16x8 qfh[2], qfl[2];
    {
        const size_t qrow = kpan + (size_t)(q0 + wq0 + l15) * HDIM;
        #pragma unroll
        for (int ds = 0; ds < 2; ++ds) {
            qfh[ds] = *(const bf16x8*)&Qh[qrow + l4 * 8 + 32 * ds];
            qfl[ds] = *(const bf16x8*)&Ql[qrow + l4 * 8 + 32 * ds];
        }
    }

    f32x4 oacc[4];
    float m_run[4], l_run[4];
    #pragma unroll
    for (int r = 0; r < 4; ++r) { m_run[r] = -1e30f; l_run[r] = 0.f; }
    #pragma unroll
    for (int nf = 0; nf < 4; ++nf) oacc[nf] = (f32x4){0.f, 0.f, 0.f, 0.f};

    const int NT = 2 * qt + 2;

    int4v pKh, pKl, pVh, pVl;
    {
        pKh = *(const int4v*)&Kh[kpan + (size_t)sr * HDIM + soff];
        pKl = *(const int4v*)&Kl[kpan + (size_t)sr * HDIM + soff];
        pVh = *(const int4v*)&Vh[vpan + (size_t)sr * SEQ + soff];
        pVl = *(const int4v*)&Vl[vpan + (size_t)sr * SEQ + soff];
    }

    for (int kt = 0; kt < NT; ++kt) {
        const int k0 = kt * 64;

        __syncthreads();

        *(int4v*)&KhS[sr][soff] = pKh;
        *(int4v*)&KlS[sr][soff] = pKl;
        *(int4v*)&VhS[sr][soff] = pVh;
        *(int4v*)&VlS[sr][soff] = pVl;

        if (kt + 1 < NT) {
            const int kn = k0 + 64;
            pKh = *(const int4v*)&Kh[kpan + (size_t)(kn + sr) * HDIM + soff];
            pKl = *(const int4v*)&Kl[kpan + (size_t)(kn + sr) * HDIM + soff];
            pVh = *(const int4v*)&Vh[vpan + (size_t)sr * SEQ + kn + soff];
            pVl = *(const int4v*)&Vl[vpan + (size_t)sr * SEQ + kn + soff];
        }
        __syncthreads();

        if (k0 > q0 + wq0 + 15) continue;

        f32x4 s[4];
        #pragma unroll
        for (int nf = 0; nf < 4; ++nf) s[nf] = (f32x4){0.f, 0.f, 0.f, 0.f};

        #pragma unroll
        for (int ds = 0; ds < 2; ++ds) {
            #pragma unroll
            for (int nf = 0; nf < 4; ++nf) {
                const bf16x8 kh = *(const bf16x8*)&KhS[nf * 16 + l15][l4 * 8 + 32 * ds];
                const bf16x8 kl = *(const bf16x8*)&KlS[nf * 16 + l15][l4 * 8 + 32 * ds];
                s[nf] = __builtin_amdgcn_mfma_f32_16x16x32_bf16(qfh[ds], kh, s[nf], 0, 0, 0);
                s[nf] = __builtin_amdgcn_mfma_f32_16x16x32_bf16(qfh[ds], kl, s[nf], 0, 0, 0);
                s[nf] = __builtin_amdgcn_mfma_f32_16x16x32_bf16(qfl[ds], kh, s[nf], 0, 0, 0);
            }
        }

        if (k0 + 63 > q0 + wq0) {
            #pragma unroll
            for (int nf = 0; nf < 4; ++nf)
                #pragma unroll
                for (int r = 0; r < 4; ++r) {
                    const int kg_ = k0 + nf * 16 + l15;
                    const int qg_ = q0 + wq0 + l4 * 4 + r;
                    if (kg_ > qg_) s[nf][r] = -1e30f;
                }
        }

        #pragma unroll
        for (int r = 0; r < 4; ++r) {
            float mx = fmaxf(fmaxf(s[0][r], s[1][r]), fmaxf(s[2][r], s[3][r]));
            mx = fmaxf(mx, __shfl_xor(mx, 1));
            mx = fmaxf(mx, __shfl_xor(mx, 2));
            mx = fmaxf(mx, __shfl_xor(mx, 4));
            mx = fmaxf(mx, __shfl_xor(mx, 8));
            const float mnew = fmaxf(m_run[r], mx);
            const float scf  = __expf(m_run[r] - mnew);
            m_run[r] = mnew;
            float ls = 0.f;
            #pragma unroll
            for (int nf = 0; nf < 4; ++nf) {
                const float p = __expf(s[nf][r] - mnew);
                s[nf][r] = p;
                ls += p;
            }
            ls += __shfl_xor(ls, 1);
            ls += __shfl_xor(ls, 2);
            ls += __shfl_xor(ls, 4);
            ls += __shfl_xor(ls, 8);
            l_run[r] = l_run[r] * scf + ls;
            #pragma unroll
            for (int nf = 0; nf < 4; ++nf) oacc[nf][r] *= scf;
        }

        #pragma unroll
        for (int nf = 0; nf < 4; ++nf)
            #pragma unroll
            for (int r = 0; r < 4; ++r) {
                const float p = s[nf][r];
                const short ph = f2bf(p);
                PhS[wq0 + l4 * 4 + r][nf * 16 + l15] = ph;
                PlS[wq0 + l4 * 4 + r][nf * 16 + l15] = f2bf(p - bf2f(ph));
            }
        asm volatile("s_waitcnt lgkmcnt(0)" ::: "memory");

        #pragma unroll
        for (int ks = 0; ks < 2; ++ks) {
            const bf16x8 pah = *(const bf16x8*)&PhS[wq0 + l15][l4 * 8 + 32 * ks];
            const bf16x8 pal = *(const bf16x8*)&PlS[wq0 + l15][l4 * 8 + 32 * ks];
            #pragma unroll
            for (int nf = 0; nf < 4; ++nf) {
                const bf16x8 vh = *(const bf16x8*)&VhS[nf * 16 + l15][l4 * 8 + 32 * ks];
                const bf16x8 vl = *(const bf16x8*)&VlS[nf * 16 + l15][l4 * 8 + 32 * ks];
                oacc[nf] = __builtin_amdgcn_mfma_f32_16x16x32_bf16(pah, vh, oacc[nf], 0, 0, 0);
                oacc[nf] = __builtin_amdgcn_mfma_f32_16x16x32_bf16(pah, vl, oacc[nf], 0, 0, 0);
                oacc[nf] = __builtin_amdgcn_mfma_f32_16x16x32_bf16(pal, vh, oacc[nf], 0, 0, 0);
            }
        }
    }

    // epilogue: normalize, fsplit, write split planes row-major [m][1024]
    #pragma unroll
    for (int r = 0; r < 4; ++r) {
        const float inv = 1.f / l_run[r];
        const int q = q0 + wq0 + l4 * 4 + r;
        const size_t row = ((size_t)(bb * SEQ + q)) * EMB + hh * HDIM;
        #pragma unroll
        for (int nf = 0; nf < 4; ++nf) {
            short hi, lo; fsplit(oacc[nf][r] * inv, hi, lo);
            Oh[row + nf * 16 + l15] = hi;
            Ol[row + nf * 16 + l15] = lo;
        }
    }
}

// ---------------------------------------------------------------------------
extern "C" void kernel_launch(void* const* d_in, const int* in_sizes, int n_in,
                              void* d_out, int out_size, void* d_ws, size_t ws_size,
                              hipStream_t stream)
{
    const float* x  = (const float*)d_in[0];
    const float* Wk = (const float*)d_in[1];
    const float* Wq = (const float*)d_in[2];
    const float* Wv = (const float*)d_in[3];
    const float* Wu = (const float*)d_in[4];
    const float* bu = (const float*)d_in[5];
    const float* kg = (const float*)d_in[6];
    const float* kb = (const float*)d_in[7];
    const float* qg = (const float*)d_in[8];
    const float* qb = (const float*)d_in[9];
    float* out = (float*)d_out;

    // ws map (64 MB):
    //  [ 0,16M) Xh|Xl   -> reused as Oh|Ol after KQV GEMMs
    //  [16,32M) Kh|Kl
    //  [32,48M) Qh|Ql
    //  [48,64M) W4h (4x2MB) | W4l (4x2MB)
    // d_out doubles as: V^T split panels (KQV z=2 out) -> final fp32 out
    char* w = (char*)d_ws;
    short* XhP = (short*)(w);
    short* XlP = (short*)(w + (8u  << 20));
    short* KhP = (short*)(w + (16u << 20));
    short* KlP = (short*)(w + (24u << 20));
    short* QhP = (short*)(w + (32u << 20));
    short* QlP = (short*)(w + (40u << 20));
    short* W4h = (short*)(w + (48u << 20));
    short* W4l = (short*)(w + (56u << 20));
    short* VTh = (short*)d_out;
    short* VTl = (short*)d_out + (4u << 20);   // +8 MB

    const float inv4 = 0.17677669529663687f;   // 1024^(-1/4)

    cvt_split<<<4096, 256, 0, stream>>>(x, XhP, XlP);
    cvt_w4<<<dim3(1024, 4), 256, 0, stream>>>(Wk, Wq, Wv, Wu, W4h, W4l);

    gemm_kqv<<<dim3(GN / 128, MROWS / 128, 3), 256, 0, stream>>>(
        XhP, XlP, W4h, W4l, kg, kb, qg, qb, inv4,
        KhP, KlP, QhP, QlP, VTh, VTl);

    attn_mfma<<<dim3(SEQ / 128, BATCH * NHEADS), 512, 0, stream>>>(
        QhP, QlP, KhP, KlP, VTh, VTl, XhP, XlP);

    gemm_out<<<dim3(GN / 128, MROWS / 64), 256, 0, stream>>>(
        XhP, XlP, W4h + (3u << 20), W4l + (3u << 20), bu, out);
}